// Round 1
// baseline (506.225 us; speedup 1.0000x reference)
//
#include <hip/hip_runtime.h>
#include <cmath>
#include <cstdint>

#define TNUM 512
#define HID 2048
#define NEXP 256
#define NGRP 8
#define KTOP 6
#define IDIM 1408
#define RNK 128
#define NPAIR (TNUM*KTOP)          // 3072
#define NRCAP 3328                 // 3072 + 8*32 padding capacity
#define MAXTILES (NRCAP/32)        // 104

static __device__ __forceinline__ float4 ld4(const float* p){ return *reinterpret_cast<const float4*>(p); }
static __device__ __forceinline__ void st4(float* p, float4 v){ *reinterpret_cast<float4*>(p) = v; }

// ---------------- workspace layout ----------------
constexpr size_t A256(size_t x){ return (x + 255) & ~(size_t)255; }
constexpr size_t OFF_LOGITS = 0;
constexpr size_t OFF_SEL    = A256(OFF_LOGITS + (size_t)TNUM*NEXP*4);
constexpr size_t OFF_WT     = A256(OFF_SEL    + (size_t)NPAIR*4);
constexpr size_t OFF_CNT    = A256(OFF_WT     + (size_t)NPAIR*4);
constexpr size_t OFF_ESTART = A256(OFF_CNT    + (size_t)NEXP*4);
constexpr size_t OFF_ECUR   = A256(OFF_ESTART + (size_t)NEXP*4);
constexpr size_t OFF_TG     = A256(OFF_ECUR   + (size_t)NEXP*4);
constexpr size_t OFF_HDR    = A256(OFF_TG     + (size_t)MAXTILES*4);
constexpr size_t OFF_ROWT   = A256(OFF_HDR    + 16);
constexpr size_t OFF_POS    = A256(OFF_ROWT   + (size_t)NRCAP*4);
constexpr size_t OFF_H1G    = A256(OFF_POS    + (size_t)NPAIR*4);
constexpr size_t OFF_H1U    = A256(OFF_H1G    + (size_t)TNUM*NGRP*RNK*4);
constexpr size_t OFF_H2G    = A256(OFF_H1U    + (size_t)TNUM*NGRP*RNK*4);
constexpr size_t OFF_H2U    = A256(OFF_H2G    + (size_t)NRCAP*RNK*4);
constexpr size_t OFF_INTER  = A256(OFF_H2U    + (size_t)NRCAP*RNK*4);
constexpr size_t OFF_D1P    = A256(OFF_INTER  + (size_t)NRCAP*IDIM*4);
constexpr size_t OFF_D2     = A256(OFF_D1P    + (size_t)2*NRCAP*RNK*4);
constexpr size_t OFF_DOWN   = A256(OFF_D2     + (size_t)NRCAP*RNK*4);
constexpr size_t WS_NEED    = OFF_DOWN + (size_t)NRCAP*HID*4;   // ~59.3 MB

// ---------------- router GEMM: logits = x @ w_router ----------------
__global__ __launch_bounds__(256) void k_router(const float* __restrict__ x,
                                                const float* __restrict__ w,
                                                float* __restrict__ logits){
  __shared__ float As[32][64];
  __shared__ float Bs[64][128];
  const int tid = threadIdx.x;
  const int t0 = blockIdx.x*32, n0 = blockIdx.y*128;
  const int tx = tid & 31, ty = tid >> 5;
  float acc[4][4] = {{0.f}};
  for(int kc = 0; kc < HID; kc += 64){
    #pragma unroll
    for(int i = 0; i < 2; i++){ int idx = tid + i*256; int r = idx>>4, k4 = (idx&15)<<2;
      st4(&As[r][k4], ld4(&x[(size_t)(t0+r)*HID + kc + k4])); }
    #pragma unroll
    for(int i = 0; i < 8; i++){ int idx = tid + i*256; int kr = idx>>5, n4 = (idx&31)<<2;
      st4(&Bs[kr][n4], ld4(&w[(size_t)(kc+kr)*NEXP + n0 + n4])); }
    __syncthreads();
    for(int kk = 0; kk < 64; kk++){
      float4 b = ld4(&Bs[kk][tx<<2]);
      #pragma unroll
      for(int r = 0; r < 4; r++){
        float a = As[(ty<<2)+r][kk];
        acc[r][0] += a*b.x; acc[r][1] += a*b.y; acc[r][2] += a*b.z; acc[r][3] += a*b.w;
      }
    }
    __syncthreads();
  }
  #pragma unroll
  for(int r = 0; r < 4; r++)
    st4(&logits[(size_t)(t0+(ty<<2)+r)*NEXP + n0 + (tx<<2)],
        make_float4(acc[r][0],acc[r][1],acc[r][2],acc[r][3]));
}

// ---------------- stage1: H1[t][g][r] = x @ U_in (dense over groups) ----------------
__global__ __launch_bounds__(256) void k_stage1(const float* __restrict__ x,
                                                const float* __restrict__ Ug,
                                                const float* __restrict__ Uu,
                                                float* __restrict__ H1g,
                                                float* __restrict__ H1u){
  __shared__ float As[32][64];
  __shared__ float Bs[64][128];
  const int tid = threadIdx.x;
  const int t0 = blockIdx.x*32;
  const int g  = blockIdx.y;
  const float* B = (blockIdx.z ? Uu : Ug) + (size_t)g*HID*RNK;
  float* out = blockIdx.z ? H1u : H1g;
  const int tx = tid & 31, ty = tid >> 5;
  float acc[4][4] = {{0.f}};
  for(int kc = 0; kc < HID; kc += 64){
    #pragma unroll
    for(int i = 0; i < 2; i++){ int idx = tid + i*256; int r = idx>>4, k4 = (idx&15)<<2;
      st4(&As[r][k4], ld4(&x[(size_t)(t0+r)*HID + kc + k4])); }
    #pragma unroll
    for(int i = 0; i < 8; i++){ int idx = tid + i*256; int kr = idx>>5, n4 = (idx&31)<<2;
      st4(&Bs[kr][n4], ld4(&B[(size_t)(kc+kr)*RNK + n4])); }
    __syncthreads();
    for(int kk = 0; kk < 64; kk++){
      float4 b = ld4(&Bs[kk][tx<<2]);
      #pragma unroll
      for(int r = 0; r < 4; r++){
        float a = As[(ty<<2)+r][kk];
        acc[r][0] += a*b.x; acc[r][1] += a*b.y; acc[r][2] += a*b.z; acc[r][3] += a*b.w;
      }
    }
    __syncthreads();
  }
  #pragma unroll
  for(int r = 0; r < 4; r++)
    st4(&out[(size_t)(t0+(ty<<2)+r)*(NGRP*RNK) + g*RNK + (tx<<2)],
        make_float4(acc[r][0],acc[r][1],acc[r][2],acc[r][3]));
}

// ---------------- per-token top-6 ----------------
__global__ __launch_bounds__(256) void k_topk(const float* __restrict__ logits,
                                              int* __restrict__ sel,
                                              float* __restrict__ wt,
                                              int* __restrict__ cnt){
  __shared__ float sv[256];
  __shared__ int   si[256];
  __shared__ float swin[KTOP];
  __shared__ int   iwin[KTOP];
  const int t = blockIdx.x, tid = threadIdx.x;
  float myv = logits[(size_t)t*NEXP + tid];
  for(int k = 0; k < KTOP; k++){
    sv[tid] = myv; si[tid] = tid; __syncthreads();
    for(int off = 128; off >= 1; off >>= 1){
      if(tid < off && sv[tid+off] > sv[tid]){ sv[tid] = sv[tid+off]; si[tid] = si[tid+off]; }
      __syncthreads();
    }
    if(tid == 0){ swin[k] = sv[0]; iwin[k] = si[0]; }
    __syncthreads();
    if(tid == iwin[k]) myv = -INFINITY;
    __syncthreads();
  }
  if(tid == 0){
    float mx = swin[0], s = 0.f, ww[KTOP];
    #pragma unroll
    for(int k = 0; k < KTOP; k++){ ww[k] = expf(swin[k]-mx); s += ww[k]; }
    float inv = 1.f/s;
    #pragma unroll
    for(int k = 0; k < KTOP; k++){
      sel[t*KTOP+k] = iwin[k];
      wt[t*KTOP+k]  = ww[k]*inv;
      atomicAdd(&cnt[iwin[k]], 1);
    }
  }
}

// ---------------- offsets / padded segments / tile->group ----------------
__global__ __launch_bounds__(256) void k_meta(const int* __restrict__ cnt,
                                              int* __restrict__ estart,
                                              int* __restrict__ ecursor,
                                              int* __restrict__ tile_group,
                                              int* __restrict__ hdr){
  __shared__ int scnt[256];
  __shared__ int gsum[8];
  __shared__ int g0[9];
  const int tid = threadIdx.x;
  scnt[tid] = cnt[tid];
  if(tid < 8) gsum[tid] = 0;
  __syncthreads();
  atomicAdd(&gsum[tid>>5], scnt[tid]);
  __syncthreads();
  if(tid == 0){
    int run = 0;
    for(int g = 0; g < 8; g++){ g0[g] = run; run += (gsum[g]+31) & ~31; }
    g0[8] = run; hdr[0] = run>>5; hdr[1] = run;
  }
  __syncthreads();
  int g = tid >> 5, s = g0[g];
  for(int i = (g<<5); i < tid; i++) s += scnt[i];
  estart[tid] = s; ecursor[tid] = s;
  const int nt = g0[8] >> 5;
  for(int t2 = tid; t2 < MAXTILES; t2 += 256){
    int gg = -1;
    if(t2 < nt){
      for(int g2 = 0; g2 < 8; g2++) if(t2*32 >= g0[g2] && t2*32 < g0[g2+1]) gg = g2;
    }
    tile_group[t2] = gg;
  }
}

// ---------------- scatter pairs into sorted rows ----------------
__global__ __launch_bounds__(256) void k_scatter(const int* __restrict__ sel,
                                                 int* __restrict__ ecursor,
                                                 int* __restrict__ row_t,
                                                 int* __restrict__ pos_of_pair){
  const int p = blockIdx.x*256 + threadIdx.x;
  if(p >= NPAIR) return;
  const int e = sel[p];
  const int pos = atomicAdd(&ecursor[e], 1);
  row_t[pos] = p / KTOP;
  pos_of_pair[p] = pos;
}

// ---------------- stage2: h2 = h1 @ core (per expert, gate/up) ----------------
__global__ __launch_bounds__(256) void k_core2(const float* __restrict__ coreA,
                                               const float* __restrict__ coreB,
                                               const float* __restrict__ H1A,
                                               const float* __restrict__ H1B,
                                               const int* __restrict__ estart,
                                               const int* __restrict__ cnt,
                                               const int* __restrict__ row_t,
                                               float* __restrict__ h2A,
                                               float* __restrict__ h2B){
  const int e = blockIdx.x;
  const int n = cnt[e];
  if(n == 0) return;
  const int j0 = estart[e], g = e >> 5;
  const float* C  = (blockIdx.y ? coreB : coreA) + (size_t)e*RNK*RNK;
  const float* H1 =  blockIdx.y ? H1B : H1A;
  float* h2 = blockIdx.y ? h2B : h2A;
  const int s = threadIdx.x & 127, half = threadIdx.x >> 7;
  for(int jb = j0; jb < j0+n; jb += 4){
    const int ja = jb + (half<<1);
    const bool ok0 = ja < j0+n, ok1 = ja+1 < j0+n;
    const float* h1a = H1 + (size_t)row_t[ok0 ? ja   : j0]*(NGRP*RNK) + g*RNK;
    const float* h1b = H1 + (size_t)row_t[ok1 ? ja+1 : j0]*(NGRP*RNK) + g*RNK;
    float a0 = 0.f, a1 = 0.f;
    for(int r = 0; r < RNK; r++){
      float c = C[r*RNK + s];
      a0 += h1a[r]*c;
      a1 += h1b[r]*c;
    }
    if(ok0) h2[(size_t)ja*RNK + s]     = a0;
    if(ok1) h2[(size_t)(ja+1)*RNK + s] = a1;
  }
}

// ---------------- stage3: inter = silu(h2g@UoutG^T) * (h2u@UoutU^T) ----------------
__global__ __launch_bounds__(256) void k_gateup(const float* __restrict__ Ug,
                                                const float* __restrict__ Uu,
                                                const float* __restrict__ h2g,
                                                const float* __restrict__ h2u,
                                                const int* __restrict__ tile_group,
                                                float* __restrict__ inter){
  __shared__ float As[32][128];
  __shared__ float Bt[128][64];
  const int g = tile_group[blockIdx.x];
  if(g < 0) return;
  const int j0 = blockIdx.x*32, i0 = blockIdx.y*64;
  const int tid = threadIdx.x, tx = tid & 15, ty = tid >> 4;
  float accg[2][4], accu[2][4];
  #pragma unroll
  for(int pass = 0; pass < 2; pass++){
    const float* h2 = pass ? h2u : h2g;
    const float* U  = (pass ? Uu : Ug) + (size_t)g*IDIM*RNK;
    float (*acc)[4] = pass ? accu : accg;
    #pragma unroll
    for(int r = 0; r < 2; r++)
      #pragma unroll
      for(int c = 0; c < 4; c++) acc[r][c] = 0.f;
    __syncthreads();
    #pragma unroll
    for(int i = 0; i < 4; i++){ int idx = tid + i*256; int r = idx>>5, k4 = (idx&31)<<2;
      st4(&As[r][k4], ld4(&h2[(size_t)(j0+r)*RNK + k4])); }
    #pragma unroll
    for(int i = 0; i < 8; i++){ int idx = tid + i*256; int ii = idx>>5, s4 = (idx&31)<<2;
      float4 v = ld4(&U[(size_t)(i0+ii)*RNK + s4]);
      Bt[s4+0][ii] = v.x; Bt[s4+1][ii] = v.y; Bt[s4+2][ii] = v.z; Bt[s4+3][ii] = v.w; }
    __syncthreads();
    for(int k = 0; k < RNK; k++){
      float4 b = ld4(&Bt[k][tx<<2]);
      float a0 = As[(ty<<1)][k], a1 = As[(ty<<1)+1][k];
      acc[0][0] += a0*b.x; acc[0][1] += a0*b.y; acc[0][2] += a0*b.z; acc[0][3] += a0*b.w;
      acc[1][0] += a1*b.x; acc[1][1] += a1*b.y; acc[1][2] += a1*b.z; acc[1][3] += a1*b.w;
    }
  }
  #pragma unroll
  for(int r = 0; r < 2; r++){
    float4 o;
    o.x = accg[r][0]/(1.f+expf(-accg[r][0]))*accu[r][0];
    o.y = accg[r][1]/(1.f+expf(-accg[r][1]))*accu[r][1];
    o.z = accg[r][2]/(1.f+expf(-accg[r][2]))*accu[r][2];
    o.w = accg[r][3]/(1.f+expf(-accg[r][3]))*accu[r][3];
    st4(&inter[(size_t)(j0+(ty<<1)+r)*IDIM + i0 + (tx<<2)], o);
  }
}

// ---------------- stage4: d1 = inter @ U_in_down (K split in 2) ----------------
__global__ __launch_bounds__(256) void k_down_in(const float* __restrict__ inter,
                                                 const float* __restrict__ Ud,
                                                 const int* __restrict__ tile_group,
                                                 float* __restrict__ d1p){
  __shared__ float As[32][64];
  __shared__ float Bs[64][128];
  const int g = tile_group[blockIdx.x];
  if(g < 0) return;
  const int j0 = blockIdx.x*32;
  const int kz = blockIdx.z;
  const float* B = Ud + (size_t)g*IDIM*RNK;
  float* out = d1p + (size_t)kz*NRCAP*RNK;
  const int tid = threadIdx.x, tx = tid & 31, ty = tid >> 5;
  float acc[4][4] = {{0.f}};
  const int kbeg = kz*(IDIM/2), kend = kbeg + (IDIM/2);
  for(int kc = kbeg; kc < kend; kc += 64){
    #pragma unroll
    for(int i = 0; i < 2; i++){ int idx = tid + i*256; int r = idx>>4, k4 = (idx&15)<<2;
      st4(&As[r][k4], ld4(&inter[(size_t)(j0+r)*IDIM + kc + k4])); }
    #pragma unroll
    for(int i = 0; i < 8; i++){ int idx = tid + i*256; int kr = idx>>5, n4 = (idx&31)<<2;
      st4(&Bs[kr][n4], ld4(&B[(size_t)(kc+kr)*RNK + n4])); }
    __syncthreads();
    for(int kk = 0; kk < 64; kk++){
      float4 b = ld4(&Bs[kk][tx<<2]);
      #pragma unroll
      for(int r = 0; r < 4; r++){
        float a = As[(ty<<2)+r][kk];
        acc[r][0] += a*b.x; acc[r][1] += a*b.y; acc[r][2] += a*b.z; acc[r][3] += a*b.w;
      }
    }
    __syncthreads();
  }
  #pragma unroll
  for(int r = 0; r < 4; r++)
    st4(&out[(size_t)(j0+(ty<<2)+r)*RNK + (tx<<2)],
        make_float4(acc[r][0],acc[r][1],acc[r][2],acc[r][3]));
}

// ---------------- stage5: d2 = (d1a+d1b) @ core_down (per expert) ----------------
__global__ __launch_bounds__(256) void k_core_down(const float* __restrict__ core,
                                                   const float* __restrict__ d1p,
                                                   const int* __restrict__ estart,
                                                   const int* __restrict__ cnt,
                                                   float* __restrict__ d2){
  const int e = blockIdx.x;
  const int n = cnt[e];
  if(n == 0) return;
  const int j0 = estart[e];
  const float* C   = core + (size_t)e*RNK*RNK;
  const float* d1b = d1p + (size_t)NRCAP*RNK;
  const int s = threadIdx.x & 127, half = threadIdx.x >> 7;
  for(int jb = j0; jb < j0+n; jb += 4){
    const int ja = jb + (half<<1);
    const bool ok0 = ja < j0+n, ok1 = ja+1 < j0+n;
    const size_t ra = (size_t)(ok0 ? ja   : j0)*RNK;
    const size_t rb = (size_t)(ok1 ? ja+1 : j0)*RNK;
    float a0 = 0.f, a1 = 0.f;
    for(int r = 0; r < RNK; r++){
      float c = C[r*RNK + s];
      a0 += (d1p[ra+r] + d1b[ra+r])*c;
      a1 += (d1p[rb+r] + d1b[rb+r])*c;
    }
    if(ok0) d2[(size_t)ja*RNK + s]     = a0;
    if(ok1) d2[(size_t)(ja+1)*RNK + s] = a1;
  }
}

// ---------------- stage6: downo = d2 @ U_out_down^T ----------------
__global__ __launch_bounds__(256) void k_down_out(const float* __restrict__ Uo,
                                                  const float* __restrict__ d2,
                                                  const int* __restrict__ tile_group,
                                                  float* __restrict__ downo){
  __shared__ float As[32][128];
  __shared__ float Bt[128][64];
  const int g = tile_group[blockIdx.x];
  if(g < 0) return;
  const int j0 = blockIdx.x*32, i0 = blockIdx.y*64;
  const int tid = threadIdx.x, tx = tid & 15, ty = tid >> 4;
  const float* U = Uo + (size_t)g*HID*RNK;
  #pragma unroll
  for(int i = 0; i < 4; i++){ int idx = tid + i*256; int r = idx>>5, k4 = (idx&31)<<2;
    st4(&As[r][k4], ld4(&d2[(size_t)(j0+r)*RNK + k4])); }
  #pragma unroll
  for(int i = 0; i < 8; i++){ int idx = tid + i*256; int ii = idx>>5, s4 = (idx&31)<<2;
    float4 v = ld4(&U[(size_t)(i0+ii)*RNK + s4]);
    Bt[s4+0][ii] = v.x; Bt[s4+1][ii] = v.y; Bt[s4+2][ii] = v.z; Bt[s4+3][ii] = v.w; }
  __syncthreads();
  float acc[2][4] = {{0.f}};
  for(int k = 0; k < RNK; k++){
    float4 b = ld4(&Bt[k][tx<<2]);
    float a0 = As[(ty<<1)][k], a1 = As[(ty<<1)+1][k];
    acc[0][0] += a0*b.x; acc[0][1] += a0*b.y; acc[0][2] += a0*b.z; acc[0][3] += a0*b.w;
    acc[1][0] += a1*b.x; acc[1][1] += a1*b.y; acc[1][2] += a1*b.z; acc[1][3] += a1*b.w;
  }
  #pragma unroll
  for(int r = 0; r < 2; r++)
    st4(&downo[(size_t)(j0+(ty<<1)+r)*HID + i0 + (tx<<2)],
        make_float4(acc[r][0],acc[r][1],acc[r][2],acc[r][3]));
}

// ---------------- combine: out[t] = sum_k wt * downo[pos(t,k)] ----------------
__global__ __launch_bounds__(256) void k_combine(const float* __restrict__ downo,
                                                 const int* __restrict__ pos_of_pair,
                                                 const float* __restrict__ wt,
                                                 float* __restrict__ out){
  const int idx = blockIdx.x*256 + threadIdx.x;      // 0..262143
  const int t  = idx >> 9;
  const int h4 = (idx & 511) << 2;
  float4 acc = make_float4(0.f,0.f,0.f,0.f);
  #pragma unroll
  for(int k = 0; k < KTOP; k++){
    const int p = t*KTOP + k;
    const float w = wt[p];
    const int pos = pos_of_pair[p];
    float4 v = ld4(&downo[(size_t)pos*HID + h4]);
    acc.x += w*v.x; acc.y += w*v.y; acc.z += w*v.z; acc.w += w*v.w;
  }
  st4(&out[(size_t)t*HID + h4], acc);
}

extern "C" void kernel_launch(void* const* d_in, const int* in_sizes, int n_in,
                              void* d_out, int out_size, void* d_ws, size_t ws_size,
                              hipStream_t stream){
  const float* x   = (const float*)d_in[0];
  const float* wr  = (const float*)d_in[1];
  const float* Uig = (const float*)d_in[2];
  const float* cg  = (const float*)d_in[3];
  const float* Uog = (const float*)d_in[4];
  const float* Uiu = (const float*)d_in[5];
  const float* cu  = (const float*)d_in[6];
  const float* Uou = (const float*)d_in[7];
  const float* Uid = (const float*)d_in[8];
  const float* cd  = (const float*)d_in[9];
  const float* Uod = (const float*)d_in[10];
  float* out = (float*)d_out;
  char* ws = (char*)d_ws;
  if(ws_size < WS_NEED) return;   // insufficient scratch — fail visibly

  float* logits = (float*)(ws + OFF_LOGITS);
  int*   sel    = (int*)  (ws + OFF_SEL);
  float* wt     = (float*)(ws + OFF_WT);
  int*   cnt    = (int*)  (ws + OFF_CNT);
  int*   estart = (int*)  (ws + OFF_ESTART);
  int*   ecur   = (int*)  (ws + OFF_ECUR);
  int*   tg     = (int*)  (ws + OFF_TG);
  int*   hdr    = (int*)  (ws + OFF_HDR);
  int*   row_t  = (int*)  (ws + OFF_ROWT);
  int*   pos    = (int*)  (ws + OFF_POS);
  float* H1g    = (float*)(ws + OFF_H1G);
  float* H1u    = (float*)(ws + OFF_H1U);
  float* h2g    = (float*)(ws + OFF_H2G);
  float* h2u    = (float*)(ws + OFF_H2U);
  float* inter  = (float*)(ws + OFF_INTER);
  float* d1p    = (float*)(ws + OFF_D1P);
  float* d2     = (float*)(ws + OFF_D2);
  float* downo  = (float*)(ws + OFF_DOWN);

  hipMemsetAsync(cnt, 0, NEXP*sizeof(int), stream);

  k_router   <<<dim3(16,2),       256, 0, stream>>>(x, wr, logits);
  k_stage1   <<<dim3(16,8,2),     256, 0, stream>>>(x, Uig, Uiu, H1g, H1u);
  k_topk     <<<512,              256, 0, stream>>>(logits, sel, wt, cnt);
  k_meta     <<<1,                256, 0, stream>>>(cnt, estart, ecur, tg, hdr);
  k_scatter  <<<12,               256, 0, stream>>>(sel, ecur, row_t, pos);
  k_core2    <<<dim3(NEXP,2),     256, 0, stream>>>(cg, cu, H1g, H1u, estart, cnt, row_t, h2g, h2u);
  k_gateup   <<<dim3(MAXTILES,22),256, 0, stream>>>(Uog, Uou, h2g, h2u, tg, inter);
  k_down_in  <<<dim3(MAXTILES,1,2),256,0, stream>>>(inter, Uid, tg, d1p);
  k_core_down<<<NEXP,             256, 0, stream>>>(cd, d1p, estart, cnt, d2);
  k_down_out <<<dim3(MAXTILES,32),256, 0, stream>>>(Uod, d2, tg, downo);
  k_combine  <<<1024,             256, 0, stream>>>(downo, pos, wt, out);
}

// Round 2
// 454.332 us; speedup vs baseline: 1.1142x; 1.1142x over previous
//
#include <hip/hip_runtime.h>
#include <cmath>
#include <cstdint>

#define TNUM 512
#define HID 2048
#define NEXP 256
#define NGRP 8
#define KTOP 6
#define IDIM 1408
#define RNK 128
#define NPAIR (TNUM*KTOP)          // 3072
#define NRCAP 3328                 // 3072 + 8*32 padding capacity
#define MAXTILES (NRCAP/32)        // 104

typedef _Float16 f16;
typedef f16  f16x8 __attribute__((ext_vector_type(8)));
typedef f16  f16x4 __attribute__((ext_vector_type(4)));
typedef float f32x4 __attribute__((ext_vector_type(4)));
#define MFMA16(a,b,c) __builtin_amdgcn_mfma_f32_16x16x32_f16((a),(b),(c),0,0,0)

static __device__ __forceinline__ float4 ld4(const float* p){ return *reinterpret_cast<const float4*>(p); }
static __device__ __forceinline__ void st4(float* p, float4 v){ *reinterpret_cast<float4*>(p) = v; }
static __device__ __forceinline__ f16x8 ldh8(const f16* p){ return *reinterpret_cast<const f16x8*>(p); }

// ---------------- workspace layout (phase-overlaid, ~59.0 MB) ----------------
constexpr size_t A256(size_t x){ return (x + 255) & ~(size_t)255; }
constexpr size_t OFF_LOGITS = 0;
constexpr size_t OFF_SEL    = A256(OFF_LOGITS + (size_t)TNUM*NEXP*4);
constexpr size_t OFF_WT     = A256(OFF_SEL    + (size_t)NPAIR*4);
constexpr size_t OFF_CNT    = A256(OFF_WT     + (size_t)NPAIR*4);
constexpr size_t OFF_ESTART = A256(OFF_CNT    + (size_t)NEXP*4);
constexpr size_t OFF_ECUR   = A256(OFF_ESTART + (size_t)NEXP*4);
constexpr size_t OFF_TG     = A256(OFF_ECUR   + (size_t)NEXP*4);
constexpr size_t OFF_HDR    = A256(OFF_TG     + (size_t)MAXTILES*4);
constexpr size_t OFF_ROWT   = A256(OFF_HDR    + 16);
constexpr size_t OFF_POS    = A256(OFF_ROWT   + (size_t)NRCAP*4);
// SegA (20 MB): phase1 = xh + U_in_gate/up transposed; later inter; later downo head
constexpr size_t OFF_SEGA   = A256(OFF_POS    + (size_t)NPAIR*4);
constexpr size_t SZ_XH      = (size_t)TNUM*HID*2;        // 2 MB / plane
constexpr size_t SZ_UTI     = (size_t)NGRP*RNK*HID*2;    // 4 MB / plane
constexpr size_t OFF_XH_HI   = OFF_SEGA;
constexpr size_t OFF_XH_LO   = OFF_XH_HI + SZ_XH;
constexpr size_t OFF_UTIG_HI = OFF_XH_LO + SZ_XH;
constexpr size_t OFF_UTIG_LO = OFF_UTIG_HI + SZ_UTI;
constexpr size_t OFF_UTIU_HI = OFF_UTIG_LO + SZ_UTI;
constexpr size_t OFF_UTIU_LO = OFF_UTIU_HI + SZ_UTI;
constexpr size_t SEGA_END    = OFF_UTIU_LO + SZ_UTI;     // SegA + 20 MB
constexpr size_t SZ_INTER    = (size_t)NRCAP*IDIM*2;     // 9.37 MB / plane
constexpr size_t OFF_INTER_HI = OFF_SEGA;                // overlays xh/Uti (dead after stage1)
constexpr size_t OFF_INTER_LO = OFF_SEGA + SZ_INTER;
// SegB (17.3 MB): U_out_gate/up + U_in_down(T)
constexpr size_t OFF_SEGB   = SEGA_END;
constexpr size_t SZ_UO      = (size_t)NGRP*IDIM*RNK*2;   // 2.88 MB / plane
constexpr size_t OFF_UOG_HI  = OFF_SEGB;
constexpr size_t OFF_UOG_LO  = OFF_UOG_HI + SZ_UO;
constexpr size_t OFF_UOU_HI  = OFF_UOG_LO + SZ_UO;
constexpr size_t OFF_UOU_LO  = OFF_UOU_HI + SZ_UO;
constexpr size_t OFF_UTID_HI = OFF_UOU_LO + SZ_UO;
constexpr size_t OFF_UTID_LO = OFF_UTID_HI + SZ_UO;
constexpr size_t SEGB_END    = OFF_UTID_LO + SZ_UO;
// downo (26 MB) overlays SegA+SegB (all dead by down_out)
constexpr size_t OFF_DOWNO  = OFF_SEGA;
// SegC (8 MB): U_out_down (alive until down_out, no overlay)
constexpr size_t OFF_SEGC   = SEGB_END;
constexpr size_t SZ_UOD     = (size_t)NGRP*HID*RNK*2;
constexpr size_t OFF_UOD_HI = OFF_SEGC;
constexpr size_t OFF_UOD_LO = OFF_UOD_HI + SZ_UOD;
// SegD (8 MB): H1 gate/up (2 K-splits each); later d1p
constexpr size_t OFF_SEGD   = OFF_SEGC + 2*SZ_UOD;
constexpr size_t SZ_H1      = (size_t)2*TNUM*NGRP*RNK*4; // 4 MB
constexpr size_t OFF_H1G    = OFF_SEGD;
constexpr size_t OFF_H1U    = OFF_H1G + SZ_H1;
constexpr size_t OFF_D1P    = OFF_SEGD;                  // 6.8 MB ≤ 8 MB (H1 dead after core2)
// SegE (3.4 MB): h2 gate/up hi/lo; later d2 hi/lo
constexpr size_t OFF_SEGE   = OFF_SEGD + 2*SZ_H1;
constexpr size_t SZ_H2      = (size_t)NRCAP*RNK*2;
constexpr size_t OFF_H2G_HI = OFF_SEGE;
constexpr size_t OFF_H2G_LO = OFF_H2G_HI + SZ_H2;
constexpr size_t OFF_H2U_HI = OFF_H2G_LO + SZ_H2;
constexpr size_t OFF_H2U_LO = OFF_H2U_HI + SZ_H2;
constexpr size_t OFF_D2_HI  = OFF_SEGE;                  // overlays h2g (dead after gateup)
constexpr size_t OFF_D2_LO  = OFF_SEGE + SZ_H2;
constexpr size_t WS_NEED    = OFF_SEGE + 4*SZ_H2;        // ≈ 59.0 MB

// ---------------- fp32 -> f16 hi/lo split converters ----------------
__global__ __launch_bounds__(256) void k_cvt(const float* __restrict__ in,
                                             f16* __restrict__ hi, f16* __restrict__ lo,
                                             int n4, float scale){
  const int i = blockIdx.x*256 + threadIdx.x;
  if(i >= n4) return;
  float4 v = ld4(in + (size_t)i*4);
  v.x *= scale; v.y *= scale; v.z *= scale; v.w *= scale;
  f16x4 H, L;
  H[0]=(f16)v.x; L[0]=(f16)(v.x-(float)H[0]);
  H[1]=(f16)v.y; L[1]=(f16)(v.y-(float)H[1]);
  H[2]=(f16)v.z; L[2]=(f16)(v.z-(float)H[2]);
  H[3]=(f16)v.w; L[3]=(f16)(v.w-(float)H[3]);
  *reinterpret_cast<f16x4*>(hi + (size_t)i*4) = H;
  *reinterpret_cast<f16x4*>(lo + (size_t)i*4) = L;
}

// in [8][R][128] fp32  ->  out [8][128][R] f16 hi/lo (scaled)
__global__ __launch_bounds__(256) void k_cvt_t(const float* __restrict__ in,
                                               f16* __restrict__ hi, f16* __restrict__ lo,
                                               int R, float scale){
  __shared__ float tile[32][33];
  const int g = blockIdx.z, r0 = blockIdx.y*32, c0 = blockIdx.x*32;
  const int tid = threadIdx.x;
  { const int r = tid>>3, c4 = (tid&7)*4;
    float4 v = ld4(in + ((size_t)g*R + r0 + r)*RNK + c0 + c4);
    tile[r][c4]=v.x; tile[r][c4+1]=v.y; tile[r][c4+2]=v.z; tile[r][c4+3]=v.w; }
  __syncthreads();
  { const int c = tid>>3, r4 = (tid&7)*4;
    f16x4 H, L;
    #pragma unroll
    for(int k = 0; k < 4; k++){
      float v = tile[r4+k][c]*scale;
      f16 h = (f16)v; H[k]=h; L[k]=(f16)(v-(float)h);
    }
    const size_t o = ((size_t)g*RNK + c0 + c)*R + r0 + r4;
    *reinterpret_cast<f16x4*>(hi + o) = H;
    *reinterpret_cast<f16x4*>(lo + o) = L; }
}

// ---------------- router GEMM (fp32, selection-critical) ----------------
__global__ __launch_bounds__(256) void k_router(const float* __restrict__ x,
                                                const float* __restrict__ w,
                                                float* __restrict__ logits){
  __shared__ float As[32][64];
  __shared__ float Bs[64][128];
  const int tid = threadIdx.x;
  const int t0 = blockIdx.x*32, n0 = blockIdx.y*128;
  const int tx = tid & 31, ty = tid >> 5;
  float acc[4][4] = {{0.f}};
  for(int kc = 0; kc < HID; kc += 64){
    #pragma unroll
    for(int i = 0; i < 2; i++){ int idx = tid + i*256; int r = idx>>4, k4 = (idx&15)<<2;
      st4(&As[r][k4], ld4(&x[(size_t)(t0+r)*HID + kc + k4])); }
    #pragma unroll
    for(int i = 0; i < 8; i++){ int idx = tid + i*256; int kr = idx>>5, n4 = (idx&31)<<2;
      st4(&Bs[kr][n4], ld4(&w[(size_t)(kc+kr)*NEXP + n0 + n4])); }
    __syncthreads();
    for(int kk = 0; kk < 64; kk++){
      float4 b = ld4(&Bs[kk][tx<<2]);
      #pragma unroll
      for(int r = 0; r < 4; r++){
        float a = As[(ty<<2)+r][kk];
        acc[r][0] += a*b.x; acc[r][1] += a*b.y; acc[r][2] += a*b.z; acc[r][3] += a*b.w;
      }
    }
    __syncthreads();
  }
  #pragma unroll
  for(int r = 0; r < 4; r++)
    st4(&logits[(size_t)(t0+(ty<<2)+r)*NEXP + n0 + (tx<<2)],
        make_float4(acc[r][0],acc[r][1],acc[r][2],acc[r][3]));
}

// ---------------- per-token top-6 ----------------
__global__ __launch_bounds__(256) void k_topk(const float* __restrict__ logits,
                                              int* __restrict__ sel,
                                              float* __restrict__ wt,
                                              int* __restrict__ cnt){
  __shared__ float sv[256];
  __shared__ int   si[256];
  __shared__ float swin[KTOP];
  __shared__ int   iwin[KTOP];
  const int t = blockIdx.x, tid = threadIdx.x;
  float myv = logits[(size_t)t*NEXP + tid];
  for(int k = 0; k < KTOP; k++){
    sv[tid] = myv; si[tid] = tid; __syncthreads();
    for(int off = 128; off >= 1; off >>= 1){
      if(tid < off && sv[tid+off] > sv[tid]){ sv[tid] = sv[tid+off]; si[tid] = si[tid+off]; }
      __syncthreads();
    }
    if(tid == 0){ swin[k] = sv[0]; iwin[k] = si[0]; }
    __syncthreads();
    if(tid == iwin[k]) myv = -INFINITY;
    __syncthreads();
  }
  if(tid == 0){
    float mx = swin[0], s = 0.f, ww[KTOP];
    #pragma unroll
    for(int k = 0; k < KTOP; k++){ ww[k] = expf(swin[k]-mx); s += ww[k]; }
    float inv = 1.f/s;
    #pragma unroll
    for(int k = 0; k < KTOP; k++){
      sel[t*KTOP+k] = iwin[k];
      wt[t*KTOP+k]  = ww[k]*inv;
      atomicAdd(&cnt[iwin[k]], 1);
    }
  }
}

// ---------------- offsets / padded segments / tile->group ----------------
__global__ __launch_bounds__(256) void k_meta(const int* __restrict__ cnt,
                                              int* __restrict__ estart,
                                              int* __restrict__ ecursor,
                                              int* __restrict__ tile_group,
                                              int* __restrict__ hdr){
  __shared__ int scnt[256];
  __shared__ int gsum[8];
  __shared__ int g0[9];
  const int tid = threadIdx.x;
  scnt[tid] = cnt[tid];
  if(tid < 8) gsum[tid] = 0;
  __syncthreads();
  atomicAdd(&gsum[tid>>5], scnt[tid]);
  __syncthreads();
  if(tid == 0){
    int run = 0;
    for(int g = 0; g < 8; g++){ g0[g] = run; run += (gsum[g]+31) & ~31; }
    g0[8] = run; hdr[0] = run>>5; hdr[1] = run;
  }
  __syncthreads();
  int g = tid >> 5, s = g0[g];
  for(int i = (g<<5); i < tid; i++) s += scnt[i];
  estart[tid] = s; ecursor[tid] = s;
  const int nt = g0[8] >> 5;
  for(int t2 = tid; t2 < MAXTILES; t2 += 256){
    int gg = -1;
    if(t2 < nt){
      for(int g2 = 0; g2 < 8; g2++) if(t2*32 >= g0[g2] && t2*32 < g0[g2+1]) gg = g2;
    }
    tile_group[t2] = gg;
  }
}

// ---------------- scatter pairs into sorted rows ----------------
__global__ __launch_bounds__(256) void k_scatter(const int* __restrict__ sel,
                                                 int* __restrict__ ecursor,
                                                 int* __restrict__ row_t,
                                                 int* __restrict__ pos_of_pair){
  const int p = blockIdx.x*256 + threadIdx.x;
  if(p >= NPAIR) return;
  const int e = sel[p];
  const int pos = atomicAdd(&ecursor[e], 1);
  row_t[pos] = p / KTOP;
  pos_of_pair[p] = pos;
}

// ---------------- stage1 MFMA: H1[ks][t][g*128+r] = x @ U_in (split-fp16 3-pass) ----------------
__global__ __launch_bounds__(256) void k_mm_stage1(
    const f16* __restrict__ xh, const f16* __restrict__ xl,
    const f16* __restrict__ Bgh, const f16* __restrict__ Bgl,
    const f16* __restrict__ Buh, const f16* __restrict__ Bul,
    float* __restrict__ H1g, float* __restrict__ H1u){
  const int t0 = blockIdx.x*32;
  const int g  = blockIdx.y;
  const int ks = blockIdx.z & 1, pu = blockIdx.z >> 1;
  const f16* Bh = (pu ? Buh : Bgh) + (size_t)g*RNK*HID;
  const f16* Bl = (pu ? Bul : Bgl) + (size_t)g*RNK*HID;
  float* out = (pu ? H1u : H1g) + (size_t)ks*TNUM*(NGRP*RNK);
  const int tid = threadIdx.x;
  const int wid = tid>>6, lane = tid&63, q = lane>>4, id = lane&15;
  const int r0 = t0 + (wid&1)*16;
  const int c0 = (wid>>1)*64;
  const int kb = ks*(HID/2);
  f32x4 acc[4];
  #pragma unroll
  for(int c = 0; c < 4; c++) acc[c] = (f32x4){0.f,0.f,0.f,0.f};
  #pragma unroll 2
  for(int kk = 0; kk < HID/2; kk += 32){
    const size_t aoff = (size_t)(r0+id)*HID + kb + kk + q*8;
    f16x8 ah = ldh8(xh + aoff);
    f16x8 al = ldh8(xl + aoff);
    #pragma unroll
    for(int c = 0; c < 4; c++){
      const size_t boff = (size_t)(c0 + c*16 + id)*HID + kb + kk + q*8;
      f16x8 bh = ldh8(Bh + boff);
      f16x8 bl = ldh8(Bl + boff);
      acc[c] = MFMA16(ah, bh, acc[c]);
      acc[c] = MFMA16(ah, bl, acc[c]);
      acc[c] = MFMA16(al, bh, acc[c]);
    }
  }
  #pragma unroll
  for(int c = 0; c < 4; c++)
    #pragma unroll
    for(int r = 0; r < 4; r++)
      out[(size_t)(r0 + q*4 + r)*(NGRP*RNK) + g*RNK + c0 + c*16 + id] = acc[c][r]*0.0625f;
}

// ---------------- core2 matvec (fp32): h2 = (H1a+H1b) @ core, write f16 hi/lo (x16) ----------------
__global__ __launch_bounds__(256) void k_core2(const float* __restrict__ coreG,
                                               const float* __restrict__ coreU,
                                               const float* __restrict__ H1g,
                                               const float* __restrict__ H1u,
                                               const int* __restrict__ estart,
                                               const int* __restrict__ cnt,
                                               const int* __restrict__ row_t,
                                               f16* __restrict__ h2g_hi, f16* __restrict__ h2g_lo,
                                               f16* __restrict__ h2u_hi, f16* __restrict__ h2u_lo){
  const int e = blockIdx.x;
  const int n = cnt[e];
  if(n == 0) return;
  const int j0 = estart[e], g = e >> 5;
  const int up = blockIdx.y;
  const float* C  = (up ? coreU : coreG) + (size_t)e*RNK*RNK;
  const float* H1 = up ? H1u : H1g;
  f16* o_hi = up ? h2u_hi : h2g_hi;
  f16* o_lo = up ? h2u_lo : h2g_lo;
  const int s = threadIdx.x & 127, half = threadIdx.x >> 7;
  for(int jb = j0; jb < j0+n; jb += 4){
    const int ja = jb + (half<<1);
    const bool ok0 = ja < j0+n, ok1 = ja+1 < j0+n;
    const float* h1a = H1 + (size_t)row_t[ok0 ? ja   : j0]*(NGRP*RNK) + g*RNK;
    const float* h1b = H1 + (size_t)row_t[ok1 ? ja+1 : j0]*(NGRP*RNK) + g*RNK;
    const float* h1a2 = h1a + (size_t)TNUM*NGRP*RNK;
    const float* h1b2 = h1b + (size_t)TNUM*NGRP*RNK;
    float a0 = 0.f, a1 = 0.f;
    for(int r = 0; r < RNK; r++){
      float c = C[r*RNK + s];
      a0 += (h1a[r]+h1a2[r])*c;
      a1 += (h1b[r]+h1b2[r])*c;
    }
    a0 *= 16.f; a1 *= 16.f;
    if(ok0){ f16 h=(f16)a0; o_hi[(size_t)ja*RNK + s]=h; o_lo[(size_t)ja*RNK + s]=(f16)(a0-(float)h); }
    if(ok1){ f16 h=(f16)a1; o_hi[(size_t)(ja+1)*RNK + s]=h; o_lo[(size_t)(ja+1)*RNK + s]=(f16)(a1-(float)h); }
  }
}

// ---------------- gateup MFMA: inter = silu(h2g@UoG^T)*(h2u@UoU^T), write f16 hi/lo (x256) ----------------
__global__ __launch_bounds__(256) void k_mm_gateup(
    const f16* __restrict__ Agh, const f16* __restrict__ Agl,
    const f16* __restrict__ Auh, const f16* __restrict__ Aul,
    const f16* __restrict__ Bgh, const f16* __restrict__ Bgl,
    const f16* __restrict__ Buh, const f16* __restrict__ Bul,
    const int* __restrict__ tg,
    f16* __restrict__ inter_hi, f16* __restrict__ inter_lo){
  const int g = tg[blockIdx.x];
  if(g < 0) return;
  const int j0 = blockIdx.x*32, n0 = blockIdx.y*128;
  const int tid = threadIdx.x;
  const int wid = tid>>6, lane = tid&63, q = lane>>4, id = lane&15;
  const int r0 = j0 + (wid&1)*16;
  const int c0 = n0 + (wid>>1)*64;
  const size_t bbase = (size_t)g*IDIM*RNK;
  f32x4 accg[4], accu[4];
  #pragma unroll
  for(int c = 0; c < 4; c++){ accg[c] = (f32x4){0.f,0.f,0.f,0.f}; accu[c] = (f32x4){0.f,0.f,0.f,0.f}; }
  #pragma unroll
  for(int kk = 0; kk < RNK; kk += 32){
    const size_t aoff = (size_t)(r0+id)*RNK + kk + q*8;
    f16x8 agh = ldh8(Agh + aoff);
    f16x8 agl = ldh8(Agl + aoff);
    f16x8 auh = ldh8(Auh + aoff);
    f16x8 aul = ldh8(Aul + aoff);
    #pragma unroll
    for(int c = 0; c < 4; c++){
      const size_t boff = bbase + (size_t)(c0 + c*16 + id)*RNK + kk + q*8;
      f16x8 bgh = ldh8(Bgh + boff);
      f16x8 bgl = ldh8(Bgl + boff);
      f16x8 buh = ldh8(Buh + boff);
      f16x8 bul = ldh8(Bul + boff);
      accg[c] = MFMA16(agh, bgh, accg[c]);
      accg[c] = MFMA16(agh, bgl, accg[c]);
      accg[c] = MFMA16(agl, bgh, accg[c]);
      accu[c] = MFMA16(auh, buh, accu[c]);
      accu[c] = MFMA16(auh, bul, accu[c]);
      accu[c] = MFMA16(aul, buh, accu[c]);
    }
  }
  #pragma unroll
  for(int c = 0; c < 4; c++)
    #pragma unroll
    for(int r = 0; r < 4; r++){
      float vg = accg[c][r] * (1.f/256.f);
      float vu = accu[c][r] * (1.f/256.f);
      float sv = vg/(1.f+expf(-vg))*vu*256.f;
      const size_t o = (size_t)(r0 + q*4 + r)*IDIM + c0 + c*16 + id;
      f16 h = (f16)sv;
      inter_hi[o] = h;
      inter_lo[o] = (f16)(sv - (float)h);
    }
}

// ---------------- down_in MFMA: d1p[ks] = inter @ U_in_down (K split 4) ----------------
__global__ __launch_bounds__(256) void k_mm_down_in(
    const f16* __restrict__ Ah, const f16* __restrict__ Al,
    const f16* __restrict__ Bh_, const f16* __restrict__ Bl_,
    const int* __restrict__ tg,
    float* __restrict__ d1p){
  const int g = tg[blockIdx.x];
  if(g < 0) return;
  const int j0 = blockIdx.x*32;
  const int ks = blockIdx.z;
  const f16* Bh = Bh_ + (size_t)g*RNK*IDIM;
  const f16* Bl = Bl_ + (size_t)g*RNK*IDIM;
  float* out = d1p + (size_t)ks*NRCAP*RNK;
  const int tid = threadIdx.x;
  const int wid = tid>>6, lane = tid&63, q = lane>>4, id = lane&15;
  const int r0 = j0 + (wid&1)*16;
  const int c0 = (wid>>1)*64;
  const int kb = ks*(IDIM/4);
  f32x4 acc[4];
  #pragma unroll
  for(int c = 0; c < 4; c++) acc[c] = (f32x4){0.f,0.f,0.f,0.f};
  #pragma unroll 2
  for(int kk = 0; kk < IDIM/4; kk += 32){
    const size_t aoff = (size_t)(r0+id)*IDIM + kb + kk + q*8;
    f16x8 ah = ldh8(Ah + aoff);
    f16x8 al = ldh8(Al + aoff);
    #pragma unroll
    for(int c = 0; c < 4; c++){
      const size_t boff = (size_t)(c0 + c*16 + id)*IDIM + kb + kk + q*8;
      f16x8 bh = ldh8(Bh + boff);
      f16x8 bl = ldh8(Bl + boff);
      acc[c] = MFMA16(ah, bh, acc[c]);
      acc[c] = MFMA16(ah, bl, acc[c]);
      acc[c] = MFMA16(al, bh, acc[c]);
    }
  }
  #pragma unroll
  for(int c = 0; c < 4; c++)
    #pragma unroll
    for(int r = 0; r < 4; r++)
      out[(size_t)(r0 + q*4 + r)*RNK + c0 + c*16 + id] = acc[c][r]*(1.f/4096.f);
}

// ---------------- core_down matvec: d2 = (sum d1p) @ core_down, write f16 hi/lo (x4096) ----------------
__global__ __launch_bounds__(256) void k_core_down(const float* __restrict__ core,
                                                   const float* __restrict__ d1p,
                                                   const int* __restrict__ estart,
                                                   const int* __restrict__ cnt,
                                                   f16* __restrict__ d2_hi, f16* __restrict__ d2_lo){
  const int e = blockIdx.x;
  const int n = cnt[e];
  if(n == 0) return;
  const int j0 = estart[e];
  const float* C = core + (size_t)e*RNK*RNK;
  const float* p1 = d1p + (size_t)NRCAP*RNK;
  const float* p2 = p1 + (size_t)NRCAP*RNK;
  const float* p3 = p2 + (size_t)NRCAP*RNK;
  const int s = threadIdx.x & 127, half = threadIdx.x >> 7;
  for(int jb = j0; jb < j0+n; jb += 4){
    const int ja = jb + (half<<1);
    const bool ok0 = ja < j0+n, ok1 = ja+1 < j0+n;
    const size_t ra = (size_t)(ok0 ? ja   : j0)*RNK;
    const size_t rb = (size_t)(ok1 ? ja+1 : j0)*RNK;
    float a0 = 0.f, a1 = 0.f;
    for(int r = 0; r < RNK; r++){
      float c = C[r*RNK + s];
      a0 += (d1p[ra+r] + p1[ra+r] + p2[ra+r] + p3[ra+r])*c;
      a1 += (d1p[rb+r] + p1[rb+r] + p2[rb+r] + p3[rb+r])*c;
    }
    a0 *= 4096.f; a1 *= 4096.f;
    if(ok0){ f16 h=(f16)a0; d2_hi[(size_t)ja*RNK + s]=h; d2_lo[(size_t)ja*RNK + s]=(f16)(a0-(float)h); }
    if(ok1){ f16 h=(f16)a1; d2_hi[(size_t)(ja+1)*RNK + s]=h; d2_lo[(size_t)(ja+1)*RNK + s]=(f16)(a1-(float)h); }
  }
}

// ---------------- down_out MFMA: downo = d2 @ U_out_down^T ----------------
__global__ __launch_bounds__(256) void k_mm_down_out(
    const f16* __restrict__ Ah, const f16* __restrict__ Al,
    const f16* __restrict__ Bh_, const f16* __restrict__ Bl_,
    const int* __restrict__ tg,
    float* __restrict__ downo){
  const int g = tg[blockIdx.x];
  if(g < 0) return;
  const int j0 = blockIdx.x*32, n0 = blockIdx.y*128;
  const f16* Bh = Bh_ + (size_t)g*HID*RNK;
  const f16* Bl = Bl_ + (size_t)g*HID*RNK;
  const int tid = threadIdx.x;
  const int wid = tid>>6, lane = tid&63, q = lane>>4, id = lane&15;
  const int r0 = j0 + (wid&1)*16;
  const int c0 = n0 + (wid>>1)*64;
  f32x4 acc[4];
  #pragma unroll
  for(int c = 0; c < 4; c++) acc[c] = (f32x4){0.f,0.f,0.f,0.f};
  #pragma unroll
  for(int kk = 0; kk < RNK; kk += 32){
    const size_t aoff = (size_t)(r0+id)*RNK + kk + q*8;
    f16x8 ah = ldh8(Ah + aoff);
    f16x8 al = ldh8(Al + aoff);
    #pragma unroll
    for(int c = 0; c < 4; c++){
      const size_t boff = (size_t)(c0 + c*16 + id)*RNK + kk + q*8;
      f16x8 bh = ldh8(Bh + boff);
      f16x8 bl = ldh8(Bl + boff);
      acc[c] = MFMA16(ah, bh, acc[c]);
      acc[c] = MFMA16(ah, bl, acc[c]);
      acc[c] = MFMA16(al, bh, acc[c]);
    }
  }
  #pragma unroll
  for(int c = 0; c < 4; c++)
    #pragma unroll
    for(int r = 0; r < 4; r++)
      downo[(size_t)(r0 + q*4 + r)*HID + c0 + c*16 + id] = acc[c][r]*(1.f/65536.f);
}

// ---------------- combine: out[t] = sum_k wt * downo[pos(t,k)] ----------------
__global__ __launch_bounds__(256) void k_combine(const float* __restrict__ downo,
                                                 const int* __restrict__ pos_of_pair,
                                                 const float* __restrict__ wt,
                                                 float* __restrict__ out){
  const int idx = blockIdx.x*256 + threadIdx.x;      // 0..262143
  const int t  = idx >> 9;
  const int h4 = (idx & 511) << 2;
  float4 acc = make_float4(0.f,0.f,0.f,0.f);
  #pragma unroll
  for(int k = 0; k < KTOP; k++){
    const int p = t*KTOP + k;
    const float w = wt[p];
    const int pos = pos_of_pair[p];
    float4 v = ld4(&downo[(size_t)pos*HID + h4]);
    acc.x += w*v.x; acc.y += w*v.y; acc.z += w*v.z; acc.w += w*v.w;
  }
  st4(&out[(size_t)t*HID + h4], acc);
}

extern "C" void kernel_launch(void* const* d_in, const int* in_sizes, int n_in,
                              void* d_out, int out_size, void* d_ws, size_t ws_size,
                              hipStream_t stream){
  const float* x   = (const float*)d_in[0];
  const float* wr  = (const float*)d_in[1];
  const float* Uig = (const float*)d_in[2];
  const float* cg  = (const float*)d_in[3];
  const float* Uog = (const float*)d_in[4];
  const float* Uiu = (const float*)d_in[5];
  const float* cu  = (const float*)d_in[6];
  const float* Uou = (const float*)d_in[7];
  const float* Uid = (const float*)d_in[8];
  const float* cd  = (const float*)d_in[9];
  const float* Uod = (const float*)d_in[10];
  float* out = (float*)d_out;
  char* ws = (char*)d_ws;
  if(ws_size < WS_NEED) return;   // insufficient scratch — fail visibly

  float* logits = (float*)(ws + OFF_LOGITS);
  int*   sel    = (int*)  (ws + OFF_SEL);
  float* wt     = (float*)(ws + OFF_WT);
  int*   cnt    = (int*)  (ws + OFF_CNT);
  int*   estart = (int*)  (ws + OFF_ESTART);
  int*   ecur   = (int*)  (ws + OFF_ECUR);
  int*   tg     = (int*)  (ws + OFF_TG);
  int*   hdr    = (int*)  (ws + OFF_HDR);
  int*   row_t  = (int*)  (ws + OFF_ROWT);
  int*   pos    = (int*)  (ws + OFF_POS);
  f16* xh_hi   = (f16*)(ws + OFF_XH_HI);
  f16* xh_lo   = (f16*)(ws + OFF_XH_LO);
  f16* utig_hi = (f16*)(ws + OFF_UTIG_HI);
  f16* utig_lo = (f16*)(ws + OFF_UTIG_LO);
  f16* utiu_hi = (f16*)(ws + OFF_UTIU_HI);
  f16* utiu_lo = (f16*)(ws + OFF_UTIU_LO);
  f16* uog_hi  = (f16*)(ws + OFF_UOG_HI);
  f16* uog_lo  = (f16*)(ws + OFF_UOG_LO);
  f16* uou_hi  = (f16*)(ws + OFF_UOU_HI);
  f16* uou_lo  = (f16*)(ws + OFF_UOU_LO);
  f16* utid_hi = (f16*)(ws + OFF_UTID_HI);
  f16* utid_lo = (f16*)(ws + OFF_UTID_LO);
  f16* uod_hi  = (f16*)(ws + OFF_UOD_HI);
  f16* uod_lo  = (f16*)(ws + OFF_UOD_LO);
  float* H1g   = (float*)(ws + OFF_H1G);
  float* H1u   = (float*)(ws + OFF_H1U);
  f16* h2g_hi  = (f16*)(ws + OFF_H2G_HI);
  f16* h2g_lo  = (f16*)(ws + OFF_H2G_LO);
  f16* h2u_hi  = (f16*)(ws + OFF_H2U_HI);
  f16* h2u_lo  = (f16*)(ws + OFF_H2U_LO);
  f16* inter_hi= (f16*)(ws + OFF_INTER_HI);
  f16* inter_lo= (f16*)(ws + OFF_INTER_LO);
  float* d1p   = (float*)(ws + OFF_D1P);
  f16* d2_hi   = (f16*)(ws + OFF_D2_HI);
  f16* d2_lo   = (f16*)(ws + OFF_D2_LO);
  float* downo = (float*)(ws + OFF_DOWNO);

  hipMemsetAsync(cnt, 0, NEXP*sizeof(int), stream);

  // weight / activation conversions (split fp16, power-of-2 scales)
  k_cvt  <<<1024, 256, 0, stream>>>(x,   xh_hi,  xh_lo,  TNUM*HID/4,      1.f);
  k_cvt  <<<1408, 256, 0, stream>>>(Uog, uog_hi, uog_lo, NGRP*IDIM*RNK/4, 16.f);
  k_cvt  <<<1408, 256, 0, stream>>>(Uou, uou_hi, uou_lo, NGRP*IDIM*RNK/4, 16.f);
  k_cvt  <<<2048, 256, 0, stream>>>(Uod, uod_hi, uod_lo, NGRP*HID*RNK/4,  16.f);
  k_cvt_t<<<dim3(4,64,8), 256, 0, stream>>>(Uig, utig_hi, utig_lo, HID,  16.f);
  k_cvt_t<<<dim3(4,64,8), 256, 0, stream>>>(Uiu, utiu_hi, utiu_lo, HID,  16.f);
  k_cvt_t<<<dim3(4,44,8), 256, 0, stream>>>(Uid, utid_hi, utid_lo, IDIM, 16.f);

  k_router   <<<dim3(16,2),        256, 0, stream>>>(x, wr, logits);
  k_topk     <<<TNUM,              256, 0, stream>>>(logits, sel, wt, cnt);
  k_meta     <<<1,                 256, 0, stream>>>(cnt, estart, ecur, tg, hdr);
  k_scatter  <<<12,                256, 0, stream>>>(sel, ecur, row_t, pos);

  k_mm_stage1<<<dim3(16,8,4),      256, 0, stream>>>(xh_hi, xh_lo, utig_hi, utig_lo,
                                                     utiu_hi, utiu_lo, H1g, H1u);
  k_core2    <<<dim3(NEXP,2),      256, 0, stream>>>(cg, cu, H1g, H1u, estart, cnt, row_t,
                                                     h2g_hi, h2g_lo, h2u_hi, h2u_lo);
  k_mm_gateup<<<dim3(MAXTILES,11), 256, 0, stream>>>(h2g_hi, h2g_lo, h2u_hi, h2u_lo,
                                                     uog_hi, uog_lo, uou_hi, uou_lo,
                                                     tg, inter_hi, inter_lo);
  k_mm_down_in<<<dim3(MAXTILES,1,4),256,0, stream>>>(inter_hi, inter_lo, utid_hi, utid_lo,
                                                     tg, d1p);
  k_core_down<<<NEXP,              256, 0, stream>>>(cd, d1p, estart, cnt, d2_hi, d2_lo);
  k_mm_down_out<<<dim3(MAXTILES,16),256,0, stream>>>(d2_hi, d2_lo, uod_hi, uod_lo, tg, downo);
  k_combine  <<<1024,              256, 0, stream>>>(downo, pos, wt, out);
}

// Round 3
// 369.463 us; speedup vs baseline: 1.3702x; 1.2297x over previous
//
#include <hip/hip_runtime.h>
#include <cmath>
#include <cstdint>

#define TNUM 512
#define HID 2048
#define NEXP 256
#define NGRP 8
#define KTOP 6
#define IDIM 1408
#define RNK 128
#define NPAIR (TNUM*KTOP)          // 3072
#define NRCAP 3328                 // 3072 + 8*32 padding capacity
#define MAXTILES (NRCAP/32)        // 104

typedef _Float16 f16;
typedef f16  f16x8 __attribute__((ext_vector_type(8)));
typedef f16  f16x4 __attribute__((ext_vector_type(4)));
typedef float f32x4 __attribute__((ext_vector_type(4)));
#define MFMA16(a,b,c) __builtin_amdgcn_mfma_f32_16x16x32_f16((a),(b),(c),0,0,0)

static __device__ __forceinline__ float4 ld4(const float* p){ return *reinterpret_cast<const float4*>(p); }
static __device__ __forceinline__ void st4(float* p, float4 v){ *reinterpret_cast<float4*>(p) = v; }
static __device__ __forceinline__ f16x8 ldh8(const f16* p){ return *reinterpret_cast<const f16x8*>(p); }

// ---------------- workspace layout (phase-overlaid, ~59.0 MB) ----------------
constexpr size_t A256(size_t x){ return (x + 255) & ~(size_t)255; }
constexpr size_t OFF_LOGITS = 0;
constexpr size_t OFF_SEL    = A256(OFF_LOGITS + (size_t)TNUM*NEXP*4);
constexpr size_t OFF_WT     = A256(OFF_SEL    + (size_t)NPAIR*4);
constexpr size_t OFF_CNT    = A256(OFF_WT     + (size_t)NPAIR*4);
constexpr size_t OFF_ESTART = A256(OFF_CNT    + (size_t)NEXP*4);
constexpr size_t OFF_ECUR   = A256(OFF_ESTART + (size_t)NEXP*4);
constexpr size_t OFF_TG     = A256(OFF_ECUR   + (size_t)NEXP*4);
constexpr size_t OFF_HDR    = A256(OFF_TG     + (size_t)MAXTILES*4);
constexpr size_t OFF_ROWT   = A256(OFF_HDR    + 16);
constexpr size_t OFF_POS    = A256(OFF_ROWT   + (size_t)NRCAP*4);
// SegA (20 MB): phase1 = xh + U_in_gate/up transposed; later inter; later downo head
constexpr size_t OFF_SEGA   = A256(OFF_POS    + (size_t)NPAIR*4);
constexpr size_t SZ_XH      = (size_t)TNUM*HID*2;        // 2 MB / plane
constexpr size_t SZ_UTI     = (size_t)NGRP*RNK*HID*2;    // 4 MB / plane
constexpr size_t OFF_XH_HI   = OFF_SEGA;
constexpr size_t OFF_XH_LO   = OFF_XH_HI + SZ_XH;
constexpr size_t OFF_UTIG_HI = OFF_XH_LO + SZ_XH;
constexpr size_t OFF_UTIG_LO = OFF_UTIG_HI + SZ_UTI;
constexpr size_t OFF_UTIU_HI = OFF_UTIG_LO + SZ_UTI;
constexpr size_t OFF_UTIU_LO = OFF_UTIU_HI + SZ_UTI;
constexpr size_t SEGA_END    = OFF_UTIU_LO + SZ_UTI;     // SegA + 20 MB
constexpr size_t SZ_INTER    = (size_t)NRCAP*IDIM*2;     // 9.37 MB / plane
constexpr size_t OFF_INTER_HI = OFF_SEGA;                // overlays xh/Uti (dead after stage1)
constexpr size_t OFF_INTER_LO = OFF_SEGA + SZ_INTER;
// SegB (17.3 MB): U_out_gate/up + U_in_down(T)
constexpr size_t OFF_SEGB   = SEGA_END;
constexpr size_t SZ_UO      = (size_t)NGRP*IDIM*RNK*2;   // 2.88 MB / plane
constexpr size_t OFF_UOG_HI  = OFF_SEGB;
constexpr size_t OFF_UOG_LO  = OFF_UOG_HI + SZ_UO;
constexpr size_t OFF_UOU_HI  = OFF_UOG_LO + SZ_UO;
constexpr size_t OFF_UOU_LO  = OFF_UOU_HI + SZ_UO;
constexpr size_t OFF_UTID_HI = OFF_UOU_LO + SZ_UO;
constexpr size_t OFF_UTID_LO = OFF_UTID_HI + SZ_UO;
constexpr size_t SEGB_END    = OFF_UTID_LO + SZ_UO;
// downo (26 MB) overlays SegA+SegB (all dead by down_out)
constexpr size_t OFF_DOWNO  = OFF_SEGA;
// SegC (8 MB): U_out_down (alive until down_out, no overlay)
constexpr size_t OFF_SEGC   = SEGB_END;
constexpr size_t SZ_UOD     = (size_t)NGRP*HID*RNK*2;
constexpr size_t OFF_UOD_HI = OFF_SEGC;
constexpr size_t OFF_UOD_LO = OFF_UOD_HI + SZ_UOD;
// SegD (8 MB): router partials (2MB, dead after topk); then H1 gate/up; later d1p
constexpr size_t OFF_SEGD   = OFF_SEGC + 2*SZ_UOD;
constexpr size_t OFF_LPART  = OFF_SEGD;                  // [4][T][E] fp32 = 2 MB
constexpr size_t SZ_H1      = (size_t)2*TNUM*NGRP*RNK*4; // 4 MB
constexpr size_t OFF_H1G    = OFF_SEGD;
constexpr size_t OFF_H1U    = OFF_H1G + SZ_H1;
constexpr size_t OFF_D1P    = OFF_SEGD;                  // 6.8 MB ≤ 8 MB (H1 dead after core2)
// SegE (3.4 MB): h2 gate/up hi/lo; later d2 hi/lo
constexpr size_t OFF_SEGE   = OFF_SEGD + 2*SZ_H1;
constexpr size_t SZ_H2      = (size_t)NRCAP*RNK*2;
constexpr size_t OFF_H2G_HI = OFF_SEGE;
constexpr size_t OFF_H2G_LO = OFF_H2G_HI + SZ_H2;
constexpr size_t OFF_H2U_HI = OFF_H2G_LO + SZ_H2;
constexpr size_t OFF_H2U_LO = OFF_H2U_HI + SZ_H2;
constexpr size_t OFF_D2_HI  = OFF_SEGE;                  // overlays h2g (dead after gateup)
constexpr size_t OFF_D2_LO  = OFF_SEGE + SZ_H2;
constexpr size_t WS_NEED    = OFF_SEGE + 4*SZ_H2;        // ≈ 59.0 MB

// ---------------- merged fp32 -> f16 hi/lo split converter (x, Uog, Uou, Uod) ----------------
// segments: x 1024 blocks | Uog 1408 | Uou 1408 | Uod 2048  => 5888 blocks total
__global__ __launch_bounds__(256) void k_cvt_all(
    const float* __restrict__ x,   const float* __restrict__ Uog,
    const float* __restrict__ Uou, const float* __restrict__ Uod,
    f16* __restrict__ xh_hi,  f16* __restrict__ xh_lo,
    f16* __restrict__ uog_hi, f16* __restrict__ uog_lo,
    f16* __restrict__ uou_hi, f16* __restrict__ uou_lo,
    f16* __restrict__ uod_hi, f16* __restrict__ uod_lo){
  const int b = blockIdx.x, tid = threadIdx.x;
  const float* in; f16* hi; f16* lo; size_t i; float scale;
  if(b < 1024){        in = x;   hi = xh_hi;  lo = xh_lo;  i = (size_t)b*256 + tid;        scale = 1.f; }
  else if(b < 2432){   in = Uog; hi = uog_hi; lo = uog_lo; i = (size_t)(b-1024)*256 + tid; scale = 16.f; }
  else if(b < 3840){   in = Uou; hi = uou_hi; lo = uou_lo; i = (size_t)(b-2432)*256 + tid; scale = 16.f; }
  else {               in = Uod; hi = uod_hi; lo = uod_lo; i = (size_t)(b-3840)*256 + tid; scale = 16.f; }
  float4 v = ld4(in + i*4);
  v.x *= scale; v.y *= scale; v.z *= scale; v.w *= scale;
  f16x4 H, L;
  H[0]=(f16)v.x; L[0]=(f16)(v.x-(float)H[0]);
  H[1]=(f16)v.y; L[1]=(f16)(v.y-(float)H[1]);
  H[2]=(f16)v.z; L[2]=(f16)(v.z-(float)H[2]);
  H[3]=(f16)v.w; L[3]=(f16)(v.w-(float)H[3]);
  *reinterpret_cast<f16x4*>(hi + i*4) = H;
  *reinterpret_cast<f16x4*>(lo + i*4) = L;
}

// merged transpose-convert: Uig/Uiu (R=2048) + Uid (R=1408): [G][R][128] -> [G][128][R]
__global__ __launch_bounds__(256) void k_cvt_t3(
    const float* __restrict__ Uig, const float* __restrict__ Uiu, const float* __restrict__ Uid,
    f16* __restrict__ ig_hi, f16* __restrict__ ig_lo,
    f16* __restrict__ iu_hi, f16* __restrict__ iu_lo,
    f16* __restrict__ id_hi, f16* __restrict__ id_lo){
  __shared__ float tile[32][33];
  const int z = blockIdx.z, tensor = z>>3, g = z&7;
  const float* in; f16* hi; f16* lo; int R;
  if(tensor == 0){ in = Uig; hi = ig_hi; lo = ig_lo; R = HID; }
  else if(tensor == 1){ in = Uiu; hi = iu_hi; lo = iu_lo; R = HID; }
  else { in = Uid; hi = id_hi; lo = id_lo; R = IDIM; }
  const int r0 = blockIdx.y*32, c0 = blockIdx.x*32;
  if(r0 >= R) return;
  const int tid = threadIdx.x;
  { const int r = tid>>3, c4 = (tid&7)*4;
    float4 v = ld4(in + ((size_t)g*R + r0 + r)*RNK + c0 + c4);
    tile[r][c4]=v.x; tile[r][c4+1]=v.y; tile[r][c4+2]=v.z; tile[r][c4+3]=v.w; }
  __syncthreads();
  { const int c = tid>>3, r4 = (tid&7)*4;
    f16x4 H, L;
    #pragma unroll
    for(int k = 0; k < 4; k++){
      float v = tile[r4+k][c]*16.f;
      f16 h = (f16)v; H[k]=h; L[k]=(f16)(v-(float)h);
    }
    const size_t o = ((size_t)g*RNK + c0 + c)*R + r0 + r4;
    *reinterpret_cast<f16x4*>(hi + o) = H;
    *reinterpret_cast<f16x4*>(lo + o) = L; }
}

// ---------------- router GEMM, K-split x4 (fp32, selection-critical) ----------------
// grid (16 t-tiles, 4 e-tiles, 4 k-chunks); lpart[kz][T][E]
__global__ __launch_bounds__(256) void k_router4(const float* __restrict__ x,
                                                 const float* __restrict__ w,
                                                 float* __restrict__ lpart){
  __shared__ float As[32][68];
  __shared__ float Bs[64][64];
  const int tid = threadIdx.x;
  const int t0 = blockIdx.x*32, e0 = blockIdx.y*64, kz = blockIdx.z;
  const int kb = kz*512;
  const int tx = tid & 15, ty = tid >> 4;
  float acc[2][4] = {{0.f}};
  for(int kc = 0; kc < 512; kc += 64){
    { const int r = tid>>3, k4 = (tid&7)<<2;   // 32 rows x 64 cols = 512 float4, 2 per thread
      st4(&As[r][k4],      ld4(&x[(size_t)(t0+r)*HID + kb + kc + k4]));
      st4(&As[r][k4+32],   ld4(&x[(size_t)(t0+r)*HID + kb + kc + k4 + 32])); }
    #pragma unroll
    for(int i = 0; i < 4; i++){ int idx = tid + i*256; int kr = idx>>4, e4 = (idx&15)<<2;
      st4(&Bs[kr][e4], ld4(&w[(size_t)(kb+kc+kr)*NEXP + e0 + e4])); }
    __syncthreads();
    for(int kk = 0; kk < 64; kk++){
      float4 b = ld4(&Bs[kk][tx<<2]);
      float a0 = As[(ty<<1)][kk], a1 = As[(ty<<1)+1][kk];
      acc[0][0] += a0*b.x; acc[0][1] += a0*b.y; acc[0][2] += a0*b.z; acc[0][3] += a0*b.w;
      acc[1][0] += a1*b.x; acc[1][1] += a1*b.y; acc[1][2] += a1*b.z; acc[1][3] += a1*b.w;
    }
    __syncthreads();
  }
  #pragma unroll
  for(int r = 0; r < 2; r++)
    st4(&lpart[((size_t)kz*TNUM + t0 + (ty<<1) + r)*NEXP + e0 + (tx<<2)],
        make_float4(acc[r][0],acc[r][1],acc[r][2],acc[r][3]));
}

// ---------------- per-token top-6 (wave-parallel argmax) ----------------
__global__ __launch_bounds__(256) void k_topk(const float* __restrict__ lpart,
                                              int* __restrict__ sel,
                                              float* __restrict__ wt,
                                              int* __restrict__ cnt){
  __shared__ float wv[4];
  __shared__ int   wi[4];
  __shared__ float swin[KTOP];
  __shared__ int   iwin[KTOP];
  const int t = blockIdx.x, tid = threadIdx.x;
  const int lane = tid & 63, wid = tid >> 6;
  const size_t base = (size_t)t*NEXP + tid;
  float v = lpart[base] + lpart[base + (size_t)TNUM*NEXP]
          + lpart[base + (size_t)2*TNUM*NEXP] + lpart[base + (size_t)3*TNUM*NEXP];
  for(int k = 0; k < KTOP; k++){
    float cv = v; int ci = tid;
    #pragma unroll
    for(int off = 1; off < 64; off <<= 1){
      float ov = __shfl_xor(cv, off);
      int   oi = __shfl_xor(ci, off);
      if(ov > cv || (ov == cv && oi < ci)){ cv = ov; ci = oi; }
    }
    if(lane == 0){ wv[wid] = cv; wi[wid] = ci; }
    __syncthreads();
    if(tid == 0){
      float bv = wv[0]; int bi = wi[0];
      #pragma unroll
      for(int w2 = 1; w2 < 4; w2++)
        if(wv[w2] > bv || (wv[w2] == bv && wi[w2] < bi)){ bv = wv[w2]; bi = wi[w2]; }
      swin[k] = bv; iwin[k] = bi;
    }
    __syncthreads();
    if(tid == iwin[k]) v = -INFINITY;
  }
  if(tid == 0){
    float mx = swin[0], s = 0.f, ww[KTOP];
    #pragma unroll
    for(int k = 0; k < KTOP; k++){ ww[k] = expf(swin[k]-mx); s += ww[k]; }
    float inv = 1.f/s;
    #pragma unroll
    for(int k = 0; k < KTOP; k++){
      sel[t*KTOP+k] = iwin[k];
      wt[t*KTOP+k]  = ww[k]*inv;
      atomicAdd(&cnt[iwin[k]], 1);
    }
  }
}

// ---------------- offsets / padded segments / tile->group ----------------
__global__ __launch_bounds__(256) void k_meta(const int* __restrict__ cnt,
                                              int* __restrict__ estart,
                                              int* __restrict__ ecursor,
                                              int* __restrict__ tile_group,
                                              int* __restrict__ hdr){
  __shared__ int scnt[256];
  __shared__ int gsum[8];
  __shared__ int g0[9];
  const int tid = threadIdx.x;
  scnt[tid] = cnt[tid];
  if(tid < 8) gsum[tid] = 0;
  __syncthreads();
  atomicAdd(&gsum[tid>>5], scnt[tid]);
  __syncthreads();
  if(tid == 0){
    int run = 0;
    for(int g = 0; g < 8; g++){ g0[g] = run; run += (gsum[g]+31) & ~31; }
    g0[8] = run; hdr[0] = run>>5; hdr[1] = run;
  }
  __syncthreads();
  int g = tid >> 5, s = g0[g];
  for(int i = (g<<5); i < tid; i++) s += scnt[i];
  estart[tid] = s; ecursor[tid] = s;
  const int nt = g0[8] >> 5;
  for(int t2 = tid; t2 < MAXTILES; t2 += 256){
    int gg = -1;
    if(t2 < nt){
      for(int g2 = 0; g2 < 8; g2++) if(t2*32 >= g0[g2] && t2*32 < g0[g2+1]) gg = g2;
    }
    tile_group[t2] = gg;
  }
}

// ---------------- scatter pairs into sorted rows ----------------
__global__ __launch_bounds__(256) void k_scatter(const int* __restrict__ sel,
                                                 int* __restrict__ ecursor,
                                                 int* __restrict__ row_t,
                                                 int* __restrict__ pos_of_pair){
  const int p = blockIdx.x*256 + threadIdx.x;
  if(p >= NPAIR) return;
  const int e = sel[p];
  const int pos = atomicAdd(&ecursor[e], 1);
  row_t[pos] = p / KTOP;
  pos_of_pair[p] = pos;
}

// ---------------- stage1 MFMA: H1[ks][t][g*128+r] = x @ U_in (split-fp16 3-pass) ----------------
__global__ __launch_bounds__(256) void k_mm_stage1(
    const f16* __restrict__ xh, const f16* __restrict__ xl,
    const f16* __restrict__ Bgh, const f16* __restrict__ Bgl,
    const f16* __restrict__ Buh, const f16* __restrict__ Bul,
    float* __restrict__ H1g, float* __restrict__ H1u){
  const int t0 = blockIdx.x*32;
  const int g  = blockIdx.y;
  const int ks = blockIdx.z & 1, pu = blockIdx.z >> 1;
  const f16* Bh = (pu ? Buh : Bgh) + (size_t)g*RNK*HID;
  const f16* Bl = (pu ? Bul : Bgl) + (size_t)g*RNK*HID;
  float* out = (pu ? H1u : H1g) + (size_t)ks*TNUM*(NGRP*RNK);
  const int tid = threadIdx.x;
  const int wid = tid>>6, lane = tid&63, q = lane>>4, id = lane&15;
  const int r0 = t0 + (wid&1)*16;
  const int c0 = (wid>>1)*64;
  const int kb = ks*(HID/2);
  f32x4 acc[4];
  #pragma unroll
  for(int c = 0; c < 4; c++) acc[c] = (f32x4){0.f,0.f,0.f,0.f};
  #pragma unroll 2
  for(int kk = 0; kk < HID/2; kk += 32){
    const size_t aoff = (size_t)(r0+id)*HID + kb + kk + q*8;
    f16x8 ah = ldh8(xh + aoff);
    f16x8 al = ldh8(xl + aoff);
    #pragma unroll
    for(int c = 0; c < 4; c++){
      const size_t boff = (size_t)(c0 + c*16 + id)*HID + kb + kk + q*8;
      f16x8 bh = ldh8(Bh + boff);
      f16x8 bl = ldh8(Bl + boff);
      acc[c] = MFMA16(ah, bh, acc[c]);
      acc[c] = MFMA16(ah, bl, acc[c]);
      acc[c] = MFMA16(al, bh, acc[c]);
    }
  }
  #pragma unroll
  for(int c = 0; c < 4; c++)
    #pragma unroll
    for(int r = 0; r < 4; r++)
      out[(size_t)(r0 + q*4 + r)*(NGRP*RNK) + g*RNK + c0 + c*16 + id] = acc[c][r]*0.0625f;
}

// ---------------- core2 matvec (fp32): h2 = (H1a+H1b) @ core, write f16 hi/lo (x16) ----------------
__global__ __launch_bounds__(256) void k_core2(const float* __restrict__ coreG,
                                               const float* __restrict__ coreU,
                                               const float* __restrict__ H1g,
                                               const float* __restrict__ H1u,
                                               const int* __restrict__ estart,
                                               const int* __restrict__ cnt,
                                               const int* __restrict__ row_t,
                                               f16* __restrict__ h2g_hi, f16* __restrict__ h2g_lo,
                                               f16* __restrict__ h2u_hi, f16* __restrict__ h2u_lo){
  const int e = blockIdx.x;
  const int n = cnt[e];
  if(n == 0) return;
  const int j0 = estart[e], g = e >> 5;
  const int up = blockIdx.y;
  const float* C  = (up ? coreU : coreG) + (size_t)e*RNK*RNK;
  const float* H1 = up ? H1u : H1g;
  f16* o_hi = up ? h2u_hi : h2g_hi;
  f16* o_lo = up ? h2u_lo : h2g_lo;
  const int s = threadIdx.x & 127, half = threadIdx.x >> 7;
  for(int jb = j0; jb < j0+n; jb += 4){
    const int ja = jb + (half<<1);
    const bool ok0 = ja < j0+n, ok1 = ja+1 < j0+n;
    const float* h1a = H1 + (size_t)row_t[ok0 ? ja   : j0]*(NGRP*RNK) + g*RNK;
    const float* h1b = H1 + (size_t)row_t[ok1 ? ja+1 : j0]*(NGRP*RNK) + g*RNK;
    const float* h1a2 = h1a + (size_t)TNUM*NGRP*RNK;
    const float* h1b2 = h1b + (size_t)TNUM*NGRP*RNK;
    float a0 = 0.f, a1 = 0.f;
    for(int r = 0; r < RNK; r++){
      float c = C[r*RNK + s];
      a0 += (h1a[r]+h1a2[r])*c;
      a1 += (h1b[r]+h1b2[r])*c;
    }
    a0 *= 16.f; a1 *= 16.f;
    if(ok0){ f16 h=(f16)a0; o_hi[(size_t)ja*RNK + s]=h; o_lo[(size_t)ja*RNK + s]=(f16)(a0-(float)h); }
    if(ok1){ f16 h=(f16)a1; o_hi[(size_t)(ja+1)*RNK + s]=h; o_lo[(size_t)(ja+1)*RNK + s]=(f16)(a1-(float)h); }
  }
}

// ---------------- gateup MFMA: inter = silu(h2g@UoG^T)*(h2u@UoU^T), write f16 hi/lo (x256) ----------------
__global__ __launch_bounds__(256) void k_mm_gateup(
    const f16* __restrict__ Agh, const f16* __restrict__ Agl,
    const f16* __restrict__ Auh, const f16* __restrict__ Aul,
    const f16* __restrict__ Bgh, const f16* __restrict__ Bgl,
    const f16* __restrict__ Buh, const f16* __restrict__ Bul,
    const int* __restrict__ tg,
    f16* __restrict__ inter_hi, f16* __restrict__ inter_lo){
  const int g = tg[blockIdx.x];
  if(g < 0) return;
  const int j0 = blockIdx.x*32, n0 = blockIdx.y*128;
  const int tid = threadIdx.x;
  const int wid = tid>>6, lane = tid&63, q = lane>>4, id = lane&15;
  const int r0 = j0 + (wid&1)*16;
  const int c0 = n0 + (wid>>1)*64;
  const size_t bbase = (size_t)g*IDIM*RNK;
  f32x4 accg[4], accu[4];
  #pragma unroll
  for(int c = 0; c < 4; c++){ accg[c] = (f32x4){0.f,0.f,0.f,0.f}; accu[c] = (f32x4){0.f,0.f,0.f,0.f}; }
  #pragma unroll
  for(int kk = 0; kk < RNK; kk += 32){
    const size_t aoff = (size_t)(r0+id)*RNK + kk + q*8;
    f16x8 agh = ldh8(Agh + aoff);
    f16x8 agl = ldh8(Agl + aoff);
    f16x8 auh = ldh8(Auh + aoff);
    f16x8 aul = ldh8(Aul + aoff);
    #pragma unroll
    for(int c = 0; c < 4; c++){
      const size_t boff = bbase + (size_t)(c0 + c*16 + id)*RNK + kk + q*8;
      f16x8 bgh = ldh8(Bgh + boff);
      f16x8 bgl = ldh8(Bgl + boff);
      f16x8 buh = ldh8(Buh + boff);
      f16x8 bul = ldh8(Bul + boff);
      accg[c] = MFMA16(agh, bgh, accg[c]);
      accg[c] = MFMA16(agh, bgl, accg[c]);
      accg[c] = MFMA16(agl, bgh, accg[c]);
      accu[c] = MFMA16(auh, buh, accu[c]);
      accu[c] = MFMA16(auh, bul, accu[c]);
      accu[c] = MFMA16(aul, buh, accu[c]);
    }
  }
  #pragma unroll
  for(int c = 0; c < 4; c++)
    #pragma unroll
    for(int r = 0; r < 4; r++){
      float vg = accg[c][r] * (1.f/256.f);
      float vu = accu[c][r] * (1.f/256.f);
      float sv = vg/(1.f+expf(-vg))*vu*256.f;
      const size_t o = (size_t)(r0 + q*4 + r)*IDIM + c0 + c*16 + id;
      f16 h = (f16)sv;
      inter_hi[o] = h;
      inter_lo[o] = (f16)(sv - (float)h);
    }
}

// ---------------- down_in MFMA: d1p[ks] = inter @ U_in_down (K split 4) ----------------
__global__ __launch_bounds__(256) void k_mm_down_in(
    const f16* __restrict__ Ah, const f16* __restrict__ Al,
    const f16* __restrict__ Bh_, const f16* __restrict__ Bl_,
    const int* __restrict__ tg,
    float* __restrict__ d1p){
  const int g = tg[blockIdx.x];
  if(g < 0) return;
  const int j0 = blockIdx.x*32;
  const int ks = blockIdx.z;
  const f16* Bh = Bh_ + (size_t)g*RNK*IDIM;
  const f16* Bl = Bl_ + (size_t)g*RNK*IDIM;
  float* out = d1p + (size_t)ks*NRCAP*RNK;
  const int tid = threadIdx.x;
  const int wid = tid>>6, lane = tid&63, q = lane>>4, id = lane&15;
  const int r0 = j0 + (wid&1)*16;
  const int c0 = (wid>>1)*64;
  const int kb = ks*(IDIM/4);
  f32x4 acc[4];
  #pragma unroll
  for(int c = 0; c < 4; c++) acc[c] = (f32x4){0.f,0.f,0.f,0.f};
  #pragma unroll 2
  for(int kk = 0; kk < IDIM/4; kk += 32){
    const size_t aoff = (size_t)(r0+id)*IDIM + kb + kk + q*8;
    f16x8 ah = ldh8(Ah + aoff);
    f16x8 al = ldh8(Al + aoff);
    #pragma unroll
    for(int c = 0; c < 4; c++){
      const size_t boff = (size_t)(c0 + c*16 + id)*IDIM + kb + kk + q*8;
      f16x8 bh = ldh8(Bh + boff);
      f16x8 bl = ldh8(Bl + boff);
      acc[c] = MFMA16(ah, bh, acc[c]);
      acc[c] = MFMA16(ah, bl, acc[c]);
      acc[c] = MFMA16(al, bh, acc[c]);
    }
  }
  #pragma unroll
  for(int c = 0; c < 4; c++)
    #pragma unroll
    for(int r = 0; r < 4; r++)
      out[(size_t)(r0 + q*4 + r)*RNK + c0 + c*16 + id] = acc[c][r]*(1.f/4096.f);
}

// ---------------- core_down matvec: d2 = (sum d1p) @ core_down, write f16 hi/lo (x4096) ----------------
__global__ __launch_bounds__(256) void k_core_down(const float* __restrict__ core,
                                                   const float* __restrict__ d1p,
                                                   const int* __restrict__ estart,
                                                   const int* __restrict__ cnt,
                                                   f16* __restrict__ d2_hi, f16* __restrict__ d2_lo){
  const int e = blockIdx.x;
  const int n = cnt[e];
  if(n == 0) return;
  const int j0 = estart[e];
  const float* C = core + (size_t)e*RNK*RNK;
  const float* p1 = d1p + (size_t)NRCAP*RNK;
  const float* p2 = p1 + (size_t)NRCAP*RNK;
  const float* p3 = p2 + (size_t)NRCAP*RNK;
  const int s = threadIdx.x & 127, half = threadIdx.x >> 7;
  for(int jb = j0; jb < j0+n; jb += 4){
    const int ja = jb + (half<<1);
    const bool ok0 = ja < j0+n, ok1 = ja+1 < j0+n;
    const size_t ra = (size_t)(ok0 ? ja   : j0)*RNK;
    const size_t rb = (size_t)(ok1 ? ja+1 : j0)*RNK;
    float a0 = 0.f, a1 = 0.f;
    for(int r = 0; r < RNK; r++){
      float c = C[r*RNK + s];
      a0 += (d1p[ra+r] + p1[ra+r] + p2[ra+r] + p3[ra+r])*c;
      a1 += (d1p[rb+r] + p1[rb+r] + p2[rb+r] + p3[rb+r])*c;
    }
    a0 *= 4096.f; a1 *= 4096.f;
    if(ok0){ f16 h=(f16)a0; d2_hi[(size_t)ja*RNK + s]=h; d2_lo[(size_t)ja*RNK + s]=(f16)(a0-(float)h); }
    if(ok1){ f16 h=(f16)a1; d2_hi[(size_t)(ja+1)*RNK + s]=h; d2_lo[(size_t)(ja+1)*RNK + s]=(f16)(a1-(float)h); }
  }
}

// ---------------- down_out MFMA: downo = d2 @ U_out_down^T ----------------
__global__ __launch_bounds__(256) void k_mm_down_out(
    const f16* __restrict__ Ah, const f16* __restrict__ Al,
    const f16* __restrict__ Bh_, const f16* __restrict__ Bl_,
    const int* __restrict__ tg,
    float* __restrict__ downo){
  const int g = tg[blockIdx.x];
  if(g < 0) return;
  const int j0 = blockIdx.x*32, n0 = blockIdx.y*128;
  const f16* Bh = Bh_ + (size_t)g*HID*RNK;
  const f16* Bl = Bl_ + (size_t)g*HID*RNK;
  const int tid = threadIdx.x;
  const int wid = tid>>6, lane = tid&63, q = lane>>4, id = lane&15;
  const int r0 = j0 + (wid&1)*16;
  const int c0 = n0 + (wid>>1)*64;
  f32x4 acc[4];
  #pragma unroll
  for(int c = 0; c < 4; c++) acc[c] = (f32x4){0.f,0.f,0.f,0.f};
  #pragma unroll
  for(int kk = 0; kk < RNK; kk += 32){
    const size_t aoff = (size_t)(r0+id)*RNK + kk + q*8;
    f16x8 ah = ldh8(Ah + aoff);
    f16x8 al = ldh8(Al + aoff);
    #pragma unroll
    for(int c = 0; c < 4; c++){
      const size_t boff = (size_t)(c0 + c*16 + id)*RNK + kk + q*8;
      f16x8 bh = ldh8(Bh + boff);
      f16x8 bl = ldh8(Bl + boff);
      acc[c] = MFMA16(ah, bh, acc[c]);
      acc[c] = MFMA16(ah, bl, acc[c]);
      acc[c] = MFMA16(al, bh, acc[c]);
    }
  }
  #pragma unroll
  for(int c = 0; c < 4; c++)
    #pragma unroll
    for(int r = 0; r < 4; r++)
      downo[(size_t)(r0 + q*4 + r)*HID + c0 + c*16 + id] = acc[c][r]*(1.f/65536.f);
}

// ---------------- combine: out[t] = sum_k wt * downo[pos(t,k)] ----------------
__global__ __launch_bounds__(256) void k_combine(const float* __restrict__ downo,
                                                 const int* __restrict__ pos_of_pair,
                                                 const float* __restrict__ wt,
                                                 float* __restrict__ out){
  const int idx = blockIdx.x*256 + threadIdx.x;      // 0..262143
  const int t  = idx >> 9;
  const int h4 = (idx & 511) << 2;
  float4 acc = make_float4(0.f,0.f,0.f,0.f);
  #pragma unroll
  for(int k = 0; k < KTOP; k++){
    const int p = t*KTOP + k;
    const float w = wt[p];
    const int pos = pos_of_pair[p];
    float4 v = ld4(&downo[(size_t)pos*HID + h4]);
    acc.x += w*v.x; acc.y += w*v.y; acc.z += w*v.z; acc.w += w*v.w;
  }
  st4(&out[(size_t)t*HID + h4], acc);
}

extern "C" void kernel_launch(void* const* d_in, const int* in_sizes, int n_in,
                              void* d_out, int out_size, void* d_ws, size_t ws_size,
                              hipStream_t stream){
  const float* x   = (const float*)d_in[0];
  const float* wr  = (const float*)d_in[1];
  const float* Uig = (const float*)d_in[2];
  const float* cg  = (const float*)d_in[3];
  const float* Uog = (const float*)d_in[4];
  const float* Uiu = (const float*)d_in[5];
  const float* cu  = (const float*)d_in[6];
  const float* Uou = (const float*)d_in[7];
  const float* Uid = (const float*)d_in[8];
  const float* cd  = (const float*)d_in[9];
  const float* Uod = (const float*)d_in[10];
  float* out = (float*)d_out;
  char* ws = (char*)d_ws;
  if(ws_size < WS_NEED) return;   // insufficient scratch — fail visibly

  int*   sel    = (int*)  (ws + OFF_SEL);
  float* wt     = (float*)(ws + OFF_WT);
  int*   cnt    = (int*)  (ws + OFF_CNT);
  int*   estart = (int*)  (ws + OFF_ESTART);
  int*   ecur   = (int*)  (ws + OFF_ECUR);
  int*   tg     = (int*)  (ws + OFF_TG);
  int*   hdr    = (int*)  (ws + OFF_HDR);
  int*   row_t  = (int*)  (ws + OFF_ROWT);
  int*   pos    = (int*)  (ws + OFF_POS);
  float* lpart  = (float*)(ws + OFF_LPART);
  f16* xh_hi   = (f16*)(ws + OFF_XH_HI);
  f16* xh_lo   = (f16*)(ws + OFF_XH_LO);
  f16* utig_hi = (f16*)(ws + OFF_UTIG_HI);
  f16* utig_lo = (f16*)(ws + OFF_UTIG_LO);
  f16* utiu_hi = (f16*)(ws + OFF_UTIU_HI);
  f16* utiu_lo = (f16*)(ws + OFF_UTIU_LO);
  f16* uog_hi  = (f16*)(ws + OFF_UOG_HI);
  f16* uog_lo  = (f16*)(ws + OFF_UOG_LO);
  f16* uou_hi  = (f16*)(ws + OFF_UOU_HI);
  f16* uou_lo  = (f16*)(ws + OFF_UOU_LO);
  f16* utid_hi = (f16*)(ws + OFF_UTID_HI);
  f16* utid_lo = (f16*)(ws + OFF_UTID_LO);
  f16* uod_hi  = (f16*)(ws + OFF_UOD_HI);
  f16* uod_lo  = (f16*)(ws + OFF_UOD_LO);
  float* H1g   = (float*)(ws + OFF_H1G);
  float* H1u   = (float*)(ws + OFF_H1U);
  f16* h2g_hi  = (f16*)(ws + OFF_H2G_HI);
  f16* h2g_lo  = (f16*)(ws + OFF_H2G_LO);
  f16* h2u_hi  = (f16*)(ws + OFF_H2U_HI);
  f16* h2u_lo  = (f16*)(ws + OFF_H2U_LO);
  f16* inter_hi= (f16*)(ws + OFF_INTER_HI);
  f16* inter_lo= (f16*)(ws + OFF_INTER_LO);
  float* d1p   = (float*)(ws + OFF_D1P);
  f16* d2_hi   = (f16*)(ws + OFF_D2_HI);
  f16* d2_lo   = (f16*)(ws + OFF_D2_LO);
  float* downo = (float*)(ws + OFF_DOWNO);

  hipMemsetAsync(cnt, 0, NEXP*sizeof(int), stream);

  // routing chain first (reads only raw inputs; lpart overlays H1 region, dead after topk)
  k_router4  <<<dim3(16,4,4),      256, 0, stream>>>(x, wr, lpart);
  k_topk     <<<TNUM,              256, 0, stream>>>(lpart, sel, wt, cnt);
  k_meta     <<<1,                 256, 0, stream>>>(cnt, estart, ecur, tg, hdr);
  k_scatter  <<<12,                256, 0, stream>>>(sel, ecur, row_t, pos);

  // weight / activation conversions (split fp16, power-of-2 scales) — 2 launches
  k_cvt_all  <<<5888,              256, 0, stream>>>(x, Uog, Uou, Uod,
                                                     xh_hi, xh_lo, uog_hi, uog_lo,
                                                     uou_hi, uou_lo, uod_hi, uod_lo);
  k_cvt_t3   <<<dim3(4,64,24),     256, 0, stream>>>(Uig, Uiu, Uid,
                                                     utig_hi, utig_lo, utiu_hi, utiu_lo,
                                                     utid_hi, utid_lo);

  k_mm_stage1<<<dim3(16,8,4),      256, 0, stream>>>(xh_hi, xh_lo, utig_hi, utig_lo,
                                                     utiu_hi, utiu_lo, H1g, H1u);
  k_core2    <<<dim3(NEXP,2),      256, 0, stream>>>(cg, cu, H1g, H1u, estart, cnt, row_t,
                                                     h2g_hi, h2g_lo, h2u_hi, h2u_lo);
  k_mm_gateup<<<dim3(MAXTILES,11), 256, 0, stream>>>(h2g_hi, h2g_lo, h2u_hi, h2u_lo,
                                                     uog_hi, uog_lo, uou_hi, uou_lo,
                                                     tg, inter_hi, inter_lo);
  k_mm_down_in<<<dim3(MAXTILES,1,4),256,0, stream>>>(inter_hi, inter_lo, utid_hi, utid_lo,
                                                     tg, d1p);
  k_core_down<<<NEXP,              256, 0, stream>>>(cd, d1p, estart, cnt, d2_hi, d2_lo);
  k_mm_down_out<<<dim3(MAXTILES,16),256,0, stream>>>(d2_hi, d2_lo, uod_hi, uod_lo, tg, downo);
  k_combine  <<<1024,              256, 0, stream>>>(downo, pos, wt, out);
}

// Round 4
// 319.473 us; speedup vs baseline: 1.5846x; 1.1565x over previous
//
#include <hip/hip_runtime.h>
#include <cmath>
#include <cstdint>

#define TNUM 512
#define HID 2048
#define NEXP 256
#define NGRP 8
#define KTOP 6
#define IDIM 1408
#define RNK 128
#define NPAIR (TNUM*KTOP)          // 3072
#define NRCAP 3328                 // 3072 + 8*32 padding capacity
#define MAXTILES (NRCAP/32)        // 104
#define KSPL1 4                    // stage1 K-split (2048/4 = 512)

typedef _Float16 f16;
typedef f16  f16x8 __attribute__((ext_vector_type(8)));
typedef f16  f16x4 __attribute__((ext_vector_type(4)));
typedef float f32x4 __attribute__((ext_vector_type(4)));
#define MFMA16(a,b,c) __builtin_amdgcn_mfma_f32_16x16x32_f16((a),(b),(c),0,0,0)

static __device__ __forceinline__ float4 ld4(const float* p){ return *reinterpret_cast<const float4*>(p); }
static __device__ __forceinline__ void st4(float* p, float4 v){ *reinterpret_cast<float4*>(p) = v; }
static __device__ __forceinline__ f16x8 ldh8(const f16* p){ return *reinterpret_cast<const f16x8*>(p); }

// ---------------- workspace layout (single fp16 plane; two overlays; ~48.4 MB) ----------------
constexpr size_t A256(size_t x){ return (x + 255) & ~(size_t)255; }
constexpr size_t OFF_SEL    = 0;
constexpr size_t OFF_WT     = A256(OFF_SEL    + (size_t)NPAIR*4);
constexpr size_t OFF_CNT    = A256(OFF_WT     + (size_t)NPAIR*4);
constexpr size_t OFF_ESTART = A256(OFF_CNT    + (size_t)NEXP*4);
constexpr size_t OFF_ECUR   = A256(OFF_ESTART + (size_t)NEXP*4);
constexpr size_t OFF_TG     = A256(OFF_ECUR   + (size_t)NEXP*4);
constexpr size_t OFF_HDR    = A256(OFF_TG     + (size_t)MAXTILES*4);
constexpr size_t OFF_ROWT   = A256(OFF_HDR    + 16);
constexpr size_t OFF_POS    = A256(OFF_ROWT   + (size_t)NRCAP*4);
constexpr size_t OFF_BIG    = A256(OFF_POS    + (size_t)NPAIR*4);

constexpr size_t SZ_XH   = (size_t)TNUM*HID*2;            // 2 MB
constexpr size_t SZ_UTI  = (size_t)NGRP*RNK*HID*2;        // 4 MB
constexpr size_t SZ_H1   = (size_t)KSPL1*TNUM*NGRP*RNK*4; // 8 MB
constexpr size_t SZ_D1P  = (size_t)4*NRCAP*RNK*4;         // 6.8 MB
constexpr size_t SZ_UO   = (size_t)NGRP*IDIM*RNK*2;       // 2.88 MB
constexpr size_t SZ_UOD  = (size_t)NGRP*HID*RNK*2;        // 4 MB
constexpr size_t SZ_H2   = (size_t)NRCAP*RNK*2;           // 0.85 MB
constexpr size_t SZ_INTER= (size_t)NRCAP*IDIM*2;          // 9.37 MB
constexpr size_t SZ_DOWNO= (size_t)NRCAP*HID*4;           // 27.3 MB

constexpr size_t OFF_XH    = OFF_BIG;                     // [cvt -> stage1]
constexpr size_t OFF_UTIG  = OFF_XH   + SZ_XH;            // [cvt -> stage1]
constexpr size_t OFF_UTIU  = OFF_UTIG + SZ_UTI;           // [cvt -> stage1]
constexpr size_t OFF_H1G   = OFF_UTIU + SZ_UTI;           // [stage1 -> core2]
constexpr size_t OFF_LPART = OFF_H1G;                     // overlay (dead before stage1)
constexpr size_t OFF_H1U   = OFF_H1G  + SZ_H1;
constexpr size_t OFF_D1P   = OFF_H1U  + SZ_H1;            // [down_in -> core_down]
constexpr size_t OFF_UOG   = OFF_D1P  + SZ_D1P;           // [cvt -> gateup]
constexpr size_t OFF_UOU   = OFF_UOG  + SZ_UO;            // [cvt -> gateup]
constexpr size_t OFF_INTER = OFF_XH;                      // overlay xh/utig/utiu (9.37 <= 10 MB)
constexpr size_t OFF_DOWNO = OFF_H1G;                     // overlay H1g/H1u/d1p/uog/uou-part (27.3 <= 29.4)
constexpr size_t OFF_UTID  = OFF_UOU  + SZ_UO;            // [cvt -> down_in]  (past downo end)
constexpr size_t OFF_UOD   = OFF_UTID + SZ_UO;            // [cvt -> down_out]
constexpr size_t OFF_H2G   = OFF_UOD  + SZ_UOD;
constexpr size_t OFF_H2U   = OFF_H2G  + SZ_H2;
constexpr size_t OFF_D2    = OFF_H2U  + SZ_H2;
constexpr size_t WS_NEED   = OFF_D2   + SZ_H2;            // ~48.4 MB
static_assert(OFF_DOWNO + SZ_DOWNO <= OFF_UTID, "downo overlay must end before utid");

// ---------------- merged fp32 -> f16 converter (x, Uog, Uou, Uod) ----------------
__global__ __launch_bounds__(256) void k_cvt_all(
    const float* __restrict__ x,   const float* __restrict__ Uog,
    const float* __restrict__ Uou, const float* __restrict__ Uod,
    f16* __restrict__ xh, f16* __restrict__ uog, f16* __restrict__ uou, f16* __restrict__ uod){
  const int b = blockIdx.x, tid = threadIdx.x;
  const float* in; f16* hi; size_t i; float scale;
  if(b < 1024){        in = x;   hi = xh;  i = (size_t)b*256 + tid;        scale = 1.f; }
  else if(b < 2432){   in = Uog; hi = uog; i = (size_t)(b-1024)*256 + tid; scale = 16.f; }
  else if(b < 3840){   in = Uou; hi = uou; i = (size_t)(b-2432)*256 + tid; scale = 16.f; }
  else {               in = Uod; hi = uod; i = (size_t)(b-3840)*256 + tid; scale = 16.f; }
  float4 v = ld4(in + i*4);
  f16x4 H;
  H[0]=(f16)(v.x*scale); H[1]=(f16)(v.y*scale); H[2]=(f16)(v.z*scale); H[3]=(f16)(v.w*scale);
  *reinterpret_cast<f16x4*>(hi + i*4) = H;
}

// merged transpose-convert: Uig/Uiu (R=2048) + Uid (R=1408): [G][R][128] -> [G][128][R] (x16)
__global__ __launch_bounds__(256) void k_cvt_t3(
    const float* __restrict__ Uig, const float* __restrict__ Uiu, const float* __restrict__ Uid,
    f16* __restrict__ ig, f16* __restrict__ iu, f16* __restrict__ idn){
  __shared__ float tile[32][33];
  const int z = blockIdx.z, tensor = z>>3, g = z&7;
  const float* in; f16* hi; int R;
  if(tensor == 0){ in = Uig; hi = ig; R = HID; }
  else if(tensor == 1){ in = Uiu; hi = iu; R = HID; }
  else { in = Uid; hi = idn; R = IDIM; }
  const int r0 = blockIdx.y*32, c0 = blockIdx.x*32;
  if(r0 >= R) return;
  const int tid = threadIdx.x;
  { const int r = tid>>3, c4 = (tid&7)*4;
    float4 v = ld4(in + ((size_t)g*R + r0 + r)*RNK + c0 + c4);
    tile[r][c4]=v.x; tile[r][c4+1]=v.y; tile[r][c4+2]=v.z; tile[r][c4+3]=v.w; }
  __syncthreads();
  { const int c = tid>>3, r4 = (tid&7)*4;
    f16x4 H;
    #pragma unroll
    for(int k = 0; k < 4; k++) H[k] = (f16)(tile[r4+k][c]*16.f);
    *reinterpret_cast<f16x4*>(hi + ((size_t)g*RNK + c0 + c)*R + r0 + r4) = H; }
}

// ---------------- router GEMM, K-split x4 (fp32, selection-critical) ----------------
__global__ __launch_bounds__(256) void k_router4(const float* __restrict__ x,
                                                 const float* __restrict__ w,
                                                 float* __restrict__ lpart){
  __shared__ float As[32][68];
  __shared__ float Bs[64][64];
  const int tid = threadIdx.x;
  const int t0 = blockIdx.x*32, e0 = blockIdx.y*64, kz = blockIdx.z;
  const int kb = kz*512;
  const int tx = tid & 15, ty = tid >> 4;
  float acc[2][4] = {{0.f}};
  for(int kc = 0; kc < 512; kc += 64){
    { const int r = tid>>3, k4 = (tid&7)<<2;
      st4(&As[r][k4],      ld4(&x[(size_t)(t0+r)*HID + kb + kc + k4]));
      st4(&As[r][k4+32],   ld4(&x[(size_t)(t0+r)*HID + kb + kc + k4 + 32])); }
    #pragma unroll
    for(int i = 0; i < 4; i++){ int idx = tid + i*256; int kr = idx>>4, e4 = (idx&15)<<2;
      st4(&Bs[kr][e4], ld4(&w[(size_t)(kb+kc+kr)*NEXP + e0 + e4])); }
    __syncthreads();
    for(int kk = 0; kk < 64; kk++){
      float4 b = ld4(&Bs[kk][tx<<2]);
      float a0 = As[(ty<<1)][kk], a1 = As[(ty<<1)+1][kk];
      acc[0][0] += a0*b.x; acc[0][1] += a0*b.y; acc[0][2] += a0*b.z; acc[0][3] += a0*b.w;
      acc[1][0] += a1*b.x; acc[1][1] += a1*b.y; acc[1][2] += a1*b.z; acc[1][3] += a1*b.w;
    }
    __syncthreads();
  }
  #pragma unroll
  for(int r = 0; r < 2; r++)
    st4(&lpart[((size_t)kz*TNUM + t0 + (ty<<1) + r)*NEXP + e0 + (tx<<2)],
        make_float4(acc[r][0],acc[r][1],acc[r][2],acc[r][3]));
}

// ---------------- per-token top-6 (wave-parallel argmax) ----------------
__global__ __launch_bounds__(256) void k_topk(const float* __restrict__ lpart,
                                              int* __restrict__ sel,
                                              float* __restrict__ wt,
                                              int* __restrict__ cnt){
  __shared__ float wv[4];
  __shared__ int   wi[4];
  __shared__ float swin[KTOP];
  __shared__ int   iwin[KTOP];
  const int t = blockIdx.x, tid = threadIdx.x;
  const int lane = tid & 63, wid = tid >> 6;
  const size_t base = (size_t)t*NEXP + tid;
  float v = lpart[base] + lpart[base + (size_t)TNUM*NEXP]
          + lpart[base + (size_t)2*TNUM*NEXP] + lpart[base + (size_t)3*TNUM*NEXP];
  for(int k = 0; k < KTOP; k++){
    float cv = v; int ci = tid;
    #pragma unroll
    for(int off = 1; off < 64; off <<= 1){
      float ov = __shfl_xor(cv, off);
      int   oi = __shfl_xor(ci, off);
      if(ov > cv || (ov == cv && oi < ci)){ cv = ov; ci = oi; }
    }
    if(lane == 0){ wv[wid] = cv; wi[wid] = ci; }
    __syncthreads();
    if(tid == 0){
      float bv = wv[0]; int bi = wi[0];
      #pragma unroll
      for(int w2 = 1; w2 < 4; w2++)
        if(wv[w2] > bv || (wv[w2] == bv && wi[w2] < bi)){ bv = wv[w2]; bi = wi[w2]; }
      swin[k] = bv; iwin[k] = bi;
    }
    __syncthreads();
    if(tid == iwin[k]) v = -INFINITY;
  }
  if(tid == 0){
    float mx = swin[0], s = 0.f, ww[KTOP];
    #pragma unroll
    for(int k = 0; k < KTOP; k++){ ww[k] = expf(swin[k]-mx); s += ww[k]; }
    float inv = 1.f/s;
    #pragma unroll
    for(int k = 0; k < KTOP; k++){
      sel[t*KTOP+k] = iwin[k];
      wt[t*KTOP+k]  = ww[k]*inv;
      atomicAdd(&cnt[iwin[k]], 1);
    }
  }
}

// ---------------- offsets / padded segments / tile->group ----------------
__global__ __launch_bounds__(256) void k_meta(const int* __restrict__ cnt,
                                              int* __restrict__ estart,
                                              int* __restrict__ ecursor,
                                              int* __restrict__ tile_group,
                                              int* __restrict__ hdr){
  __shared__ int scnt[256];
  __shared__ int gsum[8];
  __shared__ int g0[9];
  const int tid = threadIdx.x;
  scnt[tid] = cnt[tid];
  if(tid < 8) gsum[tid] = 0;
  __syncthreads();
  atomicAdd(&gsum[tid>>5], scnt[tid]);
  __syncthreads();
  if(tid == 0){
    int run = 0;
    for(int g = 0; g < 8; g++){ g0[g] = run; run += (gsum[g]+31) & ~31; }
    g0[8] = run; hdr[0] = run>>5; hdr[1] = run;
  }
  __syncthreads();
  int g = tid >> 5, s = g0[g];
  for(int i = (g<<5); i < tid; i++) s += scnt[i];
  estart[tid] = s; ecursor[tid] = s;
  const int nt = g0[8] >> 5;
  for(int t2 = tid; t2 < MAXTILES; t2 += 256){
    int gg = -1;
    if(t2 < nt){
      for(int g2 = 0; g2 < 8; g2++) if(t2*32 >= g0[g2] && t2*32 < g0[g2+1]) gg = g2;
    }
    tile_group[t2] = gg;
  }
}

// ---------------- scatter pairs into sorted rows ----------------
__global__ __launch_bounds__(256) void k_scatter(const int* __restrict__ sel,
                                                 int* __restrict__ ecursor,
                                                 int* __restrict__ row_t,
                                                 int* __restrict__ pos_of_pair){
  const int p = blockIdx.x*256 + threadIdx.x;
  if(p >= NPAIR) return;
  const int e = sel[p];
  const int pos = atomicAdd(&ecursor[e], 1);
  row_t[pos] = p / KTOP;
  pos_of_pair[p] = pos;
}

// ---------------- stage1 MFMA: H1[pu][ks][t][g*128+r] = x @ U_in (single-pass fp16) ----------------
// grid (16 t-tiles, 8 g, 8 z) where z = pu*4 + ks
__global__ __launch_bounds__(256) void k_mm_stage1(
    const f16* __restrict__ xh,
    const f16* __restrict__ Bg_, const f16* __restrict__ Bu_,
    float* __restrict__ H1g, float* __restrict__ H1u){
  const int t0 = blockIdx.x*32;
  const int g  = blockIdx.y;
  const int pu = blockIdx.z >> 2, ks = blockIdx.z & 3;
  const f16* B = (pu ? Bu_ : Bg_) + (size_t)g*RNK*HID;
  float* out = (pu ? H1u : H1g) + (size_t)ks*TNUM*(NGRP*RNK);
  const int tid = threadIdx.x;
  const int wid = tid>>6, lane = tid&63, q = lane>>4, id = lane&15;
  const int r0 = t0 + (wid&1)*16;
  const int c0 = (wid>>1)*64;
  const int kb = ks*(HID/KSPL1);
  f32x4 acc[4];
  #pragma unroll
  for(int c = 0; c < 4; c++) acc[c] = (f32x4){0.f,0.f,0.f,0.f};
  #pragma unroll 4
  for(int kk = 0; kk < HID/KSPL1; kk += 32){
    f16x8 a = ldh8(xh + (size_t)(r0+id)*HID + kb + kk + q*8);
    #pragma unroll
    for(int c = 0; c < 4; c++){
      f16x8 b = ldh8(B + (size_t)(c0 + c*16 + id)*HID + kb + kk + q*8);
      acc[c] = MFMA16(a, b, acc[c]);
    }
  }
  #pragma unroll
  for(int c = 0; c < 4; c++)
    #pragma unroll
    for(int r = 0; r < 4; r++)
      out[(size_t)(r0 + q*4 + r)*(NGRP*RNK) + g*RNK + c0 + c*16 + id] = acc[c][r]*0.0625f;
}

// ---------------- core2 matvec (fp32): h2 = (sum_ks H1) @ core, write f16 (x16) ----------------
__global__ __launch_bounds__(256) void k_core2(const float* __restrict__ coreG,
                                               const float* __restrict__ coreU,
                                               const float* __restrict__ H1g,
                                               const float* __restrict__ H1u,
                                               const int* __restrict__ estart,
                                               const int* __restrict__ cnt,
                                               const int* __restrict__ row_t,
                                               f16* __restrict__ h2g, f16* __restrict__ h2u){
  const int e = blockIdx.x;
  const int n = cnt[e];
  if(n == 0) return;
  const int j0 = estart[e], g = e >> 5;
  const int up = blockIdx.y;
  const float* C  = (up ? coreU : coreG) + (size_t)e*RNK*RNK;
  const float* H1 = up ? H1u : H1g;
  f16* o = up ? h2u : h2g;
  const size_t PL = (size_t)TNUM*NGRP*RNK;
  const int s = threadIdx.x & 127, half = threadIdx.x >> 7;
  for(int jb = j0; jb < j0+n; jb += 4){
    const int ja = jb + (half<<1);
    const bool ok0 = ja < j0+n, ok1 = ja+1 < j0+n;
    const float* ha = H1 + (size_t)row_t[ok0 ? ja   : j0]*(NGRP*RNK) + g*RNK;
    const float* hb = H1 + (size_t)row_t[ok1 ? ja+1 : j0]*(NGRP*RNK) + g*RNK;
    float a0 = 0.f, a1 = 0.f;
    for(int r = 0; r < RNK; r++){
      float c = C[r*RNK + s];
      a0 += (ha[r] + ha[r+PL] + ha[r+2*PL] + ha[r+3*PL])*c;
      a1 += (hb[r] + hb[r+PL] + hb[r+2*PL] + hb[r+3*PL])*c;
    }
    a0 *= 16.f; a1 *= 16.f;
    if(ok0) o[(size_t)ja*RNK + s]     = (f16)a0;
    if(ok1) o[(size_t)(ja+1)*RNK + s] = (f16)a1;
  }
}

// ---------------- gateup MFMA: inter = silu(h2g@UoG^T)*(h2u@UoU^T), write f16 (x256) ----------------
__global__ __launch_bounds__(256) void k_mm_gateup(
    const f16* __restrict__ Ag, const f16* __restrict__ Au,
    const f16* __restrict__ Bg, const f16* __restrict__ Bu,
    const int* __restrict__ tg,
    f16* __restrict__ inter){
  const int g = tg[blockIdx.x];
  if(g < 0) return;
  const int j0 = blockIdx.x*32, n0 = blockIdx.y*128;
  const int tid = threadIdx.x;
  const int wid = tid>>6, lane = tid&63, q = lane>>4, id = lane&15;
  const int r0 = j0 + (wid&1)*16;
  const int c0 = n0 + (wid>>1)*64;
  const size_t bbase = (size_t)g*IDIM*RNK;
  f32x4 accg[4], accu[4];
  #pragma unroll
  for(int c = 0; c < 4; c++){ accg[c] = (f32x4){0.f,0.f,0.f,0.f}; accu[c] = (f32x4){0.f,0.f,0.f,0.f}; }
  #pragma unroll 2
  for(int kk = 0; kk < RNK; kk += 32){
    const size_t aoff = (size_t)(r0+id)*RNK + kk + q*8;
    f16x8 ag = ldh8(Ag + aoff);
    f16x8 au = ldh8(Au + aoff);
    #pragma unroll
    for(int c = 0; c < 4; c++){
      const size_t boff = bbase + (size_t)(c0 + c*16 + id)*RNK + kk + q*8;
      f16x8 bg = ldh8(Bg + boff);
      f16x8 bu = ldh8(Bu + boff);
      accg[c] = MFMA16(ag, bg, accg[c]);
      accu[c] = MFMA16(au, bu, accu[c]);
    }
  }
  #pragma unroll
  for(int c = 0; c < 4; c++)
    #pragma unroll
    for(int r = 0; r < 4; r++){
      float vg = accg[c][r] * (1.f/256.f);
      float vu = accu[c][r] * (1.f/256.f);
      float sv = vg/(1.f+expf(-vg))*vu*256.f;
      inter[(size_t)(r0 + q*4 + r)*IDIM + c0 + c*16 + id] = (f16)sv;
    }
}

// ---------------- down_in MFMA: d1p[ks] = inter @ U_in_down (K split 4) ----------------
__global__ __launch_bounds__(256) void k_mm_down_in(
    const f16* __restrict__ A_, const f16* __restrict__ B_,
    const int* __restrict__ tg,
    float* __restrict__ d1p){
  const int g = tg[blockIdx.x];
  if(g < 0) return;
  const int j0 = blockIdx.x*32;
  const int ks = blockIdx.z;
  const f16* B = B_ + (size_t)g*RNK*IDIM;
  float* out = d1p + (size_t)ks*NRCAP*RNK;
  const int tid = threadIdx.x;
  const int wid = tid>>6, lane = tid&63, q = lane>>4, id = lane&15;
  const int r0 = j0 + (wid&1)*16;
  const int c0 = (wid>>1)*64;
  const int kb = ks*(IDIM/4);
  f32x4 acc[4];
  #pragma unroll
  for(int c = 0; c < 4; c++) acc[c] = (f32x4){0.f,0.f,0.f,0.f};
  #pragma unroll 2
  for(int kk = 0; kk < IDIM/4; kk += 32){
    f16x8 a = ldh8(A_ + (size_t)(r0+id)*IDIM + kb + kk + q*8);
    #pragma unroll
    for(int c = 0; c < 4; c++){
      f16x8 b = ldh8(B + (size_t)(c0 + c*16 + id)*IDIM + kb + kk + q*8);
      acc[c] = MFMA16(a, b, acc[c]);
    }
  }
  #pragma unroll
  for(int c = 0; c < 4; c++)
    #pragma unroll
    for(int r = 0; r < 4; r++)
      out[(size_t)(r0 + q*4 + r)*RNK + c0 + c*16 + id] = acc[c][r]*(1.f/4096.f);
}

// ---------------- core_down matvec: d2 = (sum d1p) @ core_down, write f16 (x4096) ----------------
__global__ __launch_bounds__(256) void k_core_down(const float* __restrict__ core,
                                                   const float* __restrict__ d1p,
                                                   const int* __restrict__ estart,
                                                   const int* __restrict__ cnt,
                                                   f16* __restrict__ d2){
  const int e = blockIdx.x;
  const int n = cnt[e];
  if(n == 0) return;
  const int j0 = estart[e];
  const float* C = core + (size_t)e*RNK*RNK;
  const size_t PL = (size_t)NRCAP*RNK;
  const int s = threadIdx.x & 127, half = threadIdx.x >> 7;
  for(int jb = j0; jb < j0+n; jb += 4){
    const int ja = jb + (half<<1);
    const bool ok0 = ja < j0+n, ok1 = ja+1 < j0+n;
    const size_t ra = (size_t)(ok0 ? ja   : j0)*RNK;
    const size_t rb = (size_t)(ok1 ? ja+1 : j0)*RNK;
    float a0 = 0.f, a1 = 0.f;
    for(int r = 0; r < RNK; r++){
      float c = C[r*RNK + s];
      a0 += (d1p[ra+r] + d1p[ra+r+PL] + d1p[ra+r+2*PL] + d1p[ra+r+3*PL])*c;
      a1 += (d1p[rb+r] + d1p[rb+r+PL] + d1p[rb+r+2*PL] + d1p[rb+r+3*PL])*c;
    }
    a0 *= 4096.f; a1 *= 4096.f;
    if(ok0) d2[(size_t)ja*RNK + s]     = (f16)a0;
    if(ok1) d2[(size_t)(ja+1)*RNK + s] = (f16)a1;
  }
}

// ---------------- down_out MFMA: downo = d2 @ U_out_down^T ----------------
__global__ __launch_bounds__(256) void k_mm_down_out(
    const f16* __restrict__ A_, const f16* __restrict__ B_,
    const int* __restrict__ tg,
    float* __restrict__ downo){
  const int g = tg[blockIdx.x];
  if(g < 0) return;
  const int j0 = blockIdx.x*32, n0 = blockIdx.y*128;
  const f16* B = B_ + (size_t)g*HID*RNK;
  const int tid = threadIdx.x;
  const int wid = tid>>6, lane = tid&63, q = lane>>4, id = lane&15;
  const int r0 = j0 + (wid&1)*16;
  const int c0 = n0 + (wid>>1)*64;
  f32x4 acc[4];
  #pragma unroll
  for(int c = 0; c < 4; c++) acc[c] = (f32x4){0.f,0.f,0.f,0.f};
  #pragma unroll 2
  for(int kk = 0; kk < RNK; kk += 32){
    f16x8 a = ldh8(A_ + (size_t)(r0+id)*RNK + kk + q*8);
    #pragma unroll
    for(int c = 0; c < 4; c++){
      f16x8 b = ldh8(B + (size_t)(c0 + c*16 + id)*RNK + kk + q*8);
      acc[c] = MFMA16(a, b, acc[c]);
    }
  }
  #pragma unroll
  for(int c = 0; c < 4; c++)
    #pragma unroll
    for(int r = 0; r < 4; r++)
      downo[(size_t)(r0 + q*4 + r)*HID + c0 + c*16 + id] = acc[c][r]*(1.f/65536.f);
}

// ---------------- combine: out[t] = sum_k wt * downo[pos(t,k)] ----------------
__global__ __launch_bounds__(256) void k_combine(const float* __restrict__ downo,
                                                 const int* __restrict__ pos_of_pair,
                                                 const float* __restrict__ wt,
                                                 float* __restrict__ out){
  const int idx = blockIdx.x*256 + threadIdx.x;      // 0..262143
  const int t  = idx >> 9;
  const int h4 = (idx & 511) << 2;
  float4 acc = make_float4(0.f,0.f,0.f,0.f);
  #pragma unroll
  for(int k = 0; k < KTOP; k++){
    const int p = t*KTOP + k;
    const float w = wt[p];
    const int pos = pos_of_pair[p];
    float4 v = ld4(&downo[(size_t)pos*HID + h4]);
    acc.x += w*v.x; acc.y += w*v.y; acc.z += w*v.z; acc.w += w*v.w;
  }
  st4(&out[(size_t)t*HID + h4], acc);
}

extern "C" void kernel_launch(void* const* d_in, const int* in_sizes, int n_in,
                              void* d_out, int out_size, void* d_ws, size_t ws_size,
                              hipStream_t stream){
  const float* x   = (const float*)d_in[0];
  const float* wr  = (const float*)d_in[1];
  const float* Uig = (const float*)d_in[2];
  const float* cg  = (const float*)d_in[3];
  const float* Uog = (const float*)d_in[4];
  const float* Uiu = (const float*)d_in[5];
  const float* cu  = (const float*)d_in[6];
  const float* Uou = (const float*)d_in[7];
  const float* Uid = (const float*)d_in[8];
  const float* cd  = (const float*)d_in[9];
  const float* Uod = (const float*)d_in[10];
  float* out = (float*)d_out;
  char* ws = (char*)d_ws;
  if(ws_size < WS_NEED) return;   // insufficient scratch — fail visibly

  int*   sel    = (int*)  (ws + OFF_SEL);
  float* wt     = (float*)(ws + OFF_WT);
  int*   cnt    = (int*)  (ws + OFF_CNT);
  int*   estart = (int*)  (ws + OFF_ESTART);
  int*   ecur   = (int*)  (ws + OFF_ECUR);
  int*   tg     = (int*)  (ws + OFF_TG);
  int*   hdr    = (int*)  (ws + OFF_HDR);
  int*   row_t  = (int*)  (ws + OFF_ROWT);
  int*   pos    = (int*)  (ws + OFF_POS);
  float* lpart  = (float*)(ws + OFF_LPART);
  f16* xh    = (f16*)(ws + OFF_XH);
  f16* utig  = (f16*)(ws + OFF_UTIG);
  f16* utiu  = (f16*)(ws + OFF_UTIU);
  f16* uog   = (f16*)(ws + OFF_UOG);
  f16* uou   = (f16*)(ws + OFF_UOU);
  f16* utid  = (f16*)(ws + OFF_UTID);
  f16* uod   = (f16*)(ws + OFF_UOD);
  float* H1g = (float*)(ws + OFF_H1G);
  float* H1u = (float*)(ws + OFF_H1U);
  f16* h2g   = (f16*)(ws + OFF_H2G);
  f16* h2u   = (f16*)(ws + OFF_H2U);
  f16* inter = (f16*)(ws + OFF_INTER);
  float* d1p = (float*)(ws + OFF_D1P);
  f16* d2    = (f16*)(ws + OFF_D2);
  float* downo = (float*)(ws + OFF_DOWNO);

  hipMemsetAsync(cnt, 0, NEXP*sizeof(int), stream);

  // routing chain (lpart overlays H1g, dead before stage1)
  k_router4  <<<dim3(16,4,4),      256, 0, stream>>>(x, wr, lpart);
  k_topk     <<<TNUM,              256, 0, stream>>>(lpart, sel, wt, cnt);
  k_meta     <<<1,                 256, 0, stream>>>(cnt, estart, ecur, tg, hdr);
  k_scatter  <<<12,                256, 0, stream>>>(sel, ecur, row_t, pos);

  // conversions (single fp16 plane, power-of-2 scales)
  k_cvt_all  <<<5888,              256, 0, stream>>>(x, Uog, Uou, Uod, xh, uog, uou, uod);
  k_cvt_t3   <<<dim3(4,64,24),     256, 0, stream>>>(Uig, Uiu, Uid, utig, utiu, utid);

  k_mm_stage1<<<dim3(16,8,8),      256, 0, stream>>>(xh, utig, utiu, H1g, H1u);
  k_core2    <<<dim3(NEXP,2),      256, 0, stream>>>(cg, cu, H1g, H1u, estart, cnt, row_t,
                                                     h2g, h2u);
  k_mm_gateup<<<dim3(MAXTILES,11), 256, 0, stream>>>(h2g, h2u, uog, uou, tg, inter);
  k_mm_down_in<<<dim3(MAXTILES,1,4),256,0, stream>>>(inter, utid, tg, d1p);
  k_core_down<<<NEXP,              256, 0, stream>>>(cd, d1p, estart, cnt, d2);
  k_mm_down_out<<<dim3(MAXTILES,16),256,0, stream>>>(d2, uod, tg, downo);
  k_combine  <<<1024,              256, 0, stream>>>(downo, pos, wt, out);
}

// Round 5
// 208.270 us; speedup vs baseline: 2.4306x; 1.5339x over previous
//
#include <hip/hip_runtime.h>
#include <cmath>
#include <cstdint>

#define TNUM 512
#define HID 2048
#define NEXP 256
#define NGRP 8
#define KTOP 6
#define IDIM 1408
#define RNK 128
#define NPAIR (TNUM*KTOP)          // 3072
#define NRCAP 3328                 // 3072 + 8*32 padding capacity
#define MAXTILES (NRCAP/32)        // 104

typedef _Float16 f16;
typedef f16  f16x8 __attribute__((ext_vector_type(8)));
typedef f16  f16x4 __attribute__((ext_vector_type(4)));
typedef float f32x4 __attribute__((ext_vector_type(4)));
#define MFMA16(a,b,c) __builtin_amdgcn_mfma_f32_16x16x32_f16((a),(b),(c),0,0,0)

static __device__ __forceinline__ float4 ld4(const float* p){ return *reinterpret_cast<const float4*>(p); }
static __device__ __forceinline__ void st4(float* p, float4 v){ *reinterpret_cast<float4*>(p) = v; }
static __device__ __forceinline__ f16x8 ldh8(const f16* p){ return *reinterpret_cast<const f16x8*>(p); }

// ---------------- workspace layout (~54 MB with overlays) ----------------
constexpr size_t A256(size_t x){ return (x + 255) & ~(size_t)255; }
constexpr size_t OFF_SEL    = 0;
constexpr size_t OFF_WT     = A256(OFF_SEL    + (size_t)NPAIR*4);
constexpr size_t OFF_CNT    = A256(OFF_WT     + (size_t)NPAIR*4);
constexpr size_t OFF_ESTART = A256(OFF_CNT    + (size_t)NEXP*4);
constexpr size_t OFF_ECUR   = A256(OFF_ESTART + (size_t)NEXP*4);
constexpr size_t OFF_TG     = A256(OFF_ECUR   + (size_t)NEXP*4);
constexpr size_t OFF_HDR    = A256(OFF_TG     + (size_t)MAXTILES*4);
constexpr size_t OFF_ROWT   = A256(OFF_HDR    + 16);
constexpr size_t OFF_POS    = A256(OFF_ROWT   + (size_t)NRCAP*4);
constexpr size_t OFF_BIG    = A256(OFF_POS    + (size_t)NPAIR*4);

constexpr size_t SZ_XH    = (size_t)TNUM*HID*2;            // 2 MB
constexpr size_t SZ_UTI   = (size_t)NGRP*RNK*HID*2;        // 4 MB
constexpr size_t SZ_CT    = (size_t)NEXP*RNK*RNK*2;        // 8 MB
constexpr size_t SZ_H1ALL = (size_t)2*TNUM*NGRP*RNK*2;     // 2 MB (pu planes, f16)
constexpr size_t SZ_UO    = (size_t)NGRP*IDIM*RNK*2;       // 2.88 MB
constexpr size_t SZ_UOD   = (size_t)NGRP*HID*RNK*2;        // 4 MB
constexpr size_t SZ_H2    = (size_t)NRCAP*RNK*2;           // 0.85 MB
constexpr size_t SZ_INTER = (size_t)NRCAP*IDIM*2;          // 9.37 MB
constexpr size_t SZ_DOWNO = (size_t)NRCAP*HID*4;           // 27.26 MB

// overlay region: [xh|utig|utiu|cgt|cut|H1] = 28 MB; downo overlays whole; inter overlays first 10 MB
constexpr size_t OFF_XH    = OFF_BIG;
constexpr size_t OFF_UTIG  = OFF_XH   + SZ_XH;
constexpr size_t OFF_UTIU  = OFF_UTIG + SZ_UTI;
constexpr size_t OFF_CGT   = OFF_UTIU + SZ_UTI;
constexpr size_t OFF_CUT   = OFF_CGT  + SZ_CT;
constexpr size_t OFF_H1    = OFF_CUT  + SZ_CT;             // f16 [2][T][G*RNK]
constexpr size_t REG_END   = OFF_H1   + SZ_H1ALL;
constexpr size_t OFF_INTER = OFF_XH;                       // lives gateup->down_in
constexpr size_t OFF_DOWNO = OFF_XH;                       // lives down_out->combine
constexpr size_t OFF_LPART = OFF_H1;                       // 2 MB, dead before stage1
// persistent tail
constexpr size_t OFF_UOG   = REG_END;
constexpr size_t OFF_UOU   = OFF_UOG  + SZ_UO;
constexpr size_t OFF_UTID  = OFF_UOU  + SZ_UO;
constexpr size_t OFF_UOD   = OFF_UTID + SZ_UO;
constexpr size_t OFF_CDT   = OFF_UOD  + SZ_UOD;
constexpr size_t OFF_H2G   = OFF_CDT  + SZ_CT;
constexpr size_t OFF_H2U   = OFF_H2G  + SZ_H2;
constexpr size_t OFF_D1    = OFF_H2U  + SZ_H2;
constexpr size_t OFF_D2    = OFF_D1   + SZ_H2;
constexpr size_t WS_NEED   = OFF_D2   + SZ_H2;             // ~54.1 MB
static_assert(OFF_DOWNO + SZ_DOWNO <= OFF_UOG, "downo overlay must end before persistent tail");
static_assert(OFF_INTER + SZ_INTER <= OFF_CGT, "inter overlay must end before cores");

// ---------------- merged fp32 -> f16 converter (x, Uog, Uou, Uod) ----------------
__global__ __launch_bounds__(256) void k_cvt_all(
    const float* __restrict__ x,   const float* __restrict__ Uog,
    const float* __restrict__ Uou, const float* __restrict__ Uod,
    f16* __restrict__ xh, f16* __restrict__ uog, f16* __restrict__ uou, f16* __restrict__ uod){
  const int b = blockIdx.x, tid = threadIdx.x;
  const float* in; f16* hi; size_t i; float scale;
  if(b < 1024){        in = x;   hi = xh;  i = (size_t)b*256 + tid;        scale = 1.f; }
  else if(b < 2432){   in = Uog; hi = uog; i = (size_t)(b-1024)*256 + tid; scale = 16.f; }
  else if(b < 3840){   in = Uou; hi = uou; i = (size_t)(b-2432)*256 + tid; scale = 16.f; }
  else {               in = Uod; hi = uod; i = (size_t)(b-3840)*256 + tid; scale = 16.f; }
  float4 v = ld4(in + i*4);
  f16x4 H;
  H[0]=(f16)(v.x*scale); H[1]=(f16)(v.y*scale); H[2]=(f16)(v.z*scale); H[3]=(f16)(v.w*scale);
  *reinterpret_cast<f16x4*>(hi + i*4) = H;
}

// merged transpose-convert: Uig/Uiu (R=2048) + Uid (R=1408): [G][R][128] -> [G][128][R] (x16)
__global__ __launch_bounds__(256) void k_cvt_t3(
    const float* __restrict__ Uig, const float* __restrict__ Uiu, const float* __restrict__ Uid,
    f16* __restrict__ ig, f16* __restrict__ iu, f16* __restrict__ idn){
  __shared__ float tile[32][33];
  const int z = blockIdx.z, tensor = z>>3, g = z&7;
  const float* in; f16* hi; int R;
  if(tensor == 0){ in = Uig; hi = ig; R = HID; }
  else if(tensor == 1){ in = Uiu; hi = iu; R = HID; }
  else { in = Uid; hi = idn; R = IDIM; }
  const int r0 = blockIdx.y*32, c0 = blockIdx.x*32;
  if(r0 >= R) return;
  const int tid = threadIdx.x;
  { const int r = tid>>3, c4 = (tid&7)*4;
    float4 v = ld4(in + ((size_t)g*R + r0 + r)*RNK + c0 + c4);
    tile[r][c4]=v.x; tile[r][c4+1]=v.y; tile[r][c4+2]=v.z; tile[r][c4+3]=v.w; }
  __syncthreads();
  { const int c = tid>>3, r4 = (tid&7)*4;
    f16x4 H;
    #pragma unroll
    for(int k = 0; k < 4; k++) H[k] = (f16)(tile[r4+k][c]*16.f);
    *reinterpret_cast<f16x4*>(hi + ((size_t)g*RNK + c0 + c)*R + r0 + r4) = H; }
}

// core transpose-convert: [E][r1][r2] -> f16 [E][r2][r1] (x16); grid (4,4,3*256)
__global__ __launch_bounds__(256) void k_cvt_core(
    const float* __restrict__ cg, const float* __restrict__ cu, const float* __restrict__ cd,
    f16* __restrict__ cgt, f16* __restrict__ cut, f16* __restrict__ cdt){
  __shared__ float tile[32][33];
  const int z = blockIdx.z, tensor = z>>8, e = z&255;
  const float* in; f16* o;
  if(tensor == 0){ in = cg; o = cgt; }
  else if(tensor == 1){ in = cu; o = cut; }
  else { in = cd; o = cdt; }
  in += (size_t)e*RNK*RNK; o += (size_t)e*RNK*RNK;
  const int r0 = blockIdx.y*32, c0 = blockIdx.x*32;
  const int tid = threadIdx.x;
  { const int r = tid>>3, c4 = (tid&7)*4;
    float4 v = ld4(in + (size_t)(r0+r)*RNK + c0 + c4);
    tile[r][c4]=v.x; tile[r][c4+1]=v.y; tile[r][c4+2]=v.z; tile[r][c4+3]=v.w; }
  __syncthreads();
  { const int c = tid>>3, r4 = (tid&7)*4;
    f16x4 H;
    #pragma unroll
    for(int k = 0; k < 4; k++) H[k] = (f16)(tile[r4+k][c]*16.f);
    *reinterpret_cast<f16x4*>(o + (size_t)(c0+c)*RNK + r0 + r4) = H; }
}

// ---------------- router GEMM, K-split x4 (fp32, selection-critical) ----------------
__global__ __launch_bounds__(256) void k_router4(const float* __restrict__ x,
                                                 const float* __restrict__ w,
                                                 float* __restrict__ lpart){
  __shared__ float As[32][68];
  __shared__ float Bs[64][64];
  const int tid = threadIdx.x;
  const int t0 = blockIdx.x*32, e0 = blockIdx.y*64, kz = blockIdx.z;
  const int kb = kz*512;
  const int tx = tid & 15, ty = tid >> 4;
  float acc[2][4] = {{0.f}};
  for(int kc = 0; kc < 512; kc += 64){
    { const int r = tid>>3, k4 = (tid&7)<<2;
      st4(&As[r][k4],      ld4(&x[(size_t)(t0+r)*HID + kb + kc + k4]));
      st4(&As[r][k4+32],   ld4(&x[(size_t)(t0+r)*HID + kb + kc + k4 + 32])); }
    #pragma unroll
    for(int i = 0; i < 4; i++){ int idx = tid + i*256; int kr = idx>>4, e4 = (idx&15)<<2;
      st4(&Bs[kr][e4], ld4(&w[(size_t)(kb+kc+kr)*NEXP + e0 + e4])); }
    __syncthreads();
    for(int kk = 0; kk < 64; kk++){
      float4 b = ld4(&Bs[kk][tx<<2]);
      float a0 = As[(ty<<1)][kk], a1 = As[(ty<<1)+1][kk];
      acc[0][0] += a0*b.x; acc[0][1] += a0*b.y; acc[0][2] += a0*b.z; acc[0][3] += a0*b.w;
      acc[1][0] += a1*b.x; acc[1][1] += a1*b.y; acc[1][2] += a1*b.z; acc[1][3] += a1*b.w;
    }
    __syncthreads();
  }
  #pragma unroll
  for(int r = 0; r < 2; r++)
    st4(&lpart[((size_t)kz*TNUM + t0 + (ty<<1) + r)*NEXP + e0 + (tx<<2)],
        make_float4(acc[r][0],acc[r][1],acc[r][2],acc[r][3]));
}

// ---------------- per-token top-6 (wave-parallel argmax) ----------------
__global__ __launch_bounds__(256) void k_topk(const float* __restrict__ lpart,
                                              int* __restrict__ sel,
                                              float* __restrict__ wt,
                                              int* __restrict__ cnt){
  __shared__ float wv[4];
  __shared__ int   wi[4];
  __shared__ float swin[KTOP];
  __shared__ int   iwin[KTOP];
  const int t = blockIdx.x, tid = threadIdx.x;
  const int lane = tid & 63, wid = tid >> 6;
  const size_t base = (size_t)t*NEXP + tid;
  float v = lpart[base] + lpart[base + (size_t)TNUM*NEXP]
          + lpart[base + (size_t)2*TNUM*NEXP] + lpart[base + (size_t)3*TNUM*NEXP];
  for(int k = 0; k < KTOP; k++){
    float cv = v; int ci = tid;
    #pragma unroll
    for(int off = 1; off < 64; off <<= 1){
      float ov = __shfl_xor(cv, off);
      int   oi = __shfl_xor(ci, off);
      if(ov > cv || (ov == cv && oi < ci)){ cv = ov; ci = oi; }
    }
    if(lane == 0){ wv[wid] = cv; wi[wid] = ci; }
    __syncthreads();
    if(tid == 0){
      float bv = wv[0]; int bi = wi[0];
      #pragma unroll
      for(int w2 = 1; w2 < 4; w2++)
        if(wv[w2] > bv || (wv[w2] == bv && wi[w2] < bi)){ bv = wv[w2]; bi = wi[w2]; }
      swin[k] = bv; iwin[k] = bi;
    }
    __syncthreads();
    if(tid == iwin[k]) v = -INFINITY;
  }
  if(tid == 0){
    float mx = swin[0], s = 0.f, ww[KTOP];
    #pragma unroll
    for(int k = 0; k < KTOP; k++){ ww[k] = expf(swin[k]-mx); s += ww[k]; }
    float inv = 1.f/s;
    #pragma unroll
    for(int k = 0; k < KTOP; k++){
      sel[t*KTOP+k] = iwin[k];
      wt[t*KTOP+k]  = ww[k]*inv;
      atomicAdd(&cnt[iwin[k]], 1);
    }
  }
}

// ---------------- offsets / padded segments / tile->group ----------------
__global__ __launch_bounds__(256) void k_meta(const int* __restrict__ cnt,
                                              int* __restrict__ estart,
                                              int* __restrict__ ecursor,
                                              int* __restrict__ tile_group,
                                              int* __restrict__ hdr){
  __shared__ int scnt[256];
  __shared__ int gsum[8];
  __shared__ int g0[9];
  const int tid = threadIdx.x;
  scnt[tid] = cnt[tid];
  if(tid < 8) gsum[tid] = 0;
  __syncthreads();
  atomicAdd(&gsum[tid>>5], scnt[tid]);
  __syncthreads();
  if(tid == 0){
    int run = 0;
    for(int g = 0; g < 8; g++){ g0[g] = run; run += (gsum[g]+31) & ~31; }
    g0[8] = run; hdr[0] = run>>5; hdr[1] = run;
  }
  __syncthreads();
  int g = tid >> 5, s = g0[g];
  for(int i = (g<<5); i < tid; i++) s += scnt[i];
  estart[tid] = s; ecursor[tid] = s;
  const int nt = g0[8] >> 5;
  for(int t2 = tid; t2 < MAXTILES; t2 += 256){
    int gg = -1;
    if(t2 < nt){
      for(int g2 = 0; g2 < 8; g2++) if(t2*32 >= g0[g2] && t2*32 < g0[g2+1]) gg = g2;
    }
    tile_group[t2] = gg;
  }
}

// ---------------- scatter pairs into sorted rows ----------------
__global__ __launch_bounds__(256) void k_scatter(const int* __restrict__ sel,
                                                 int* __restrict__ ecursor,
                                                 int* __restrict__ row_t,
                                                 int* __restrict__ pos_of_pair){
  const int p = blockIdx.x*256 + threadIdx.x;
  if(p >= NPAIR) return;
  const int e = sel[p];
  const int pos = atomicAdd(&ecursor[e], 1);
  row_t[pos] = p / KTOP;
  pos_of_pair[p] = pos;
}

// ---------------- stage1 MFMA: H1[pu][t][g*128+c] f16(x16) = x @ U_in ----------------
// grid (16 t-tiles, 8 g, 8 z) where z = pu*4 + cs (column split)
__global__ __launch_bounds__(256) void k_mm_stage1(
    const f16* __restrict__ xh,
    const f16* __restrict__ Bg_, const f16* __restrict__ Bu_,
    f16* __restrict__ H1){
  const int t0 = blockIdx.x*32;
  const int g  = blockIdx.y;
  const int pu = blockIdx.z >> 2, cs = blockIdx.z & 3;
  const f16* B = (pu ? Bu_ : Bg_) + (size_t)g*RNK*HID;
  f16* out = H1 + (size_t)pu*TNUM*(NGRP*RNK);
  const int tid = threadIdx.x;
  const int wid = tid>>6, lane = tid&63, q = lane>>4, id = lane&15;
  const int row0 = t0 + (wid&1)*16;
  const int col0 = cs*32 + (wid>>1)*16;
  f32x4 acc = (f32x4){0.f,0.f,0.f,0.f};
  #pragma unroll 8
  for(int kk = 0; kk < HID; kk += 32){
    f16x8 a = ldh8(xh + (size_t)(row0+id)*HID + kk + q*8);
    f16x8 b = ldh8(B  + (size_t)(col0+id)*HID + kk + q*8);
    acc = MFMA16(a, b, acc);
  }
  #pragma unroll
  for(int r = 0; r < 4; r++)
    out[(size_t)(row0 + q*4 + r)*(NGRP*RNK) + g*RNK + col0 + id] = (f16)acc[r];
}

// ---------------- core2 MFMA: h2(x256) = H1(x16) @ Ct(x16); gathered rows ----------------
// grid (NEXP, 2); wave w covers cols [w*32, w*32+32); 16-row tiles
__global__ __launch_bounds__(256) void k_core2(
    const f16* __restrict__ Cg, const f16* __restrict__ Cu,
    const f16* __restrict__ H1,
    const int* __restrict__ estart, const int* __restrict__ cnt,
    const int* __restrict__ row_t,
    f16* __restrict__ h2g, f16* __restrict__ h2u){
  const int e = blockIdx.x, up = blockIdx.y;
  const int n = cnt[e];
  if(n == 0) return;
  const int j0 = estart[e], g = e >> 5;
  const f16* C = (up ? Cu : Cg) + (size_t)e*RNK*RNK;
  const f16* A = H1 + (size_t)up*TNUM*(NGRP*RNK);
  f16* o = up ? h2u : h2g;
  const int tid = threadIdx.x;
  const int wid = tid>>6, lane = tid&63, q = lane>>4, id = lane&15;
  for(int rt = 0; rt*16 < n; rt++){
    const int jrow = j0 + rt*16 + id;
    const int jj = jrow < j0+n ? jrow : j0;
    const f16* arow = A + (size_t)row_t[jj]*(NGRP*RNK) + g*RNK;
    f32x4 acc0 = (f32x4){0.f,0.f,0.f,0.f};
    f32x4 acc1 = (f32x4){0.f,0.f,0.f,0.f};
    #pragma unroll
    for(int kk = 0; kk < RNK; kk += 32){
      f16x8 a = ldh8(arow + kk + q*8);
      f16x8 b0 = ldh8(C + (size_t)(wid*32 + id)*RNK      + kk + q*8);
      f16x8 b1 = ldh8(C + (size_t)(wid*32 + 16 + id)*RNK + kk + q*8);
      acc0 = MFMA16(a, b0, acc0);
      acc1 = MFMA16(a, b1, acc1);
    }
    #pragma unroll
    for(int r = 0; r < 4; r++){
      const int j = j0 + rt*16 + q*4 + r;
      if(j < j0+n){
        o[(size_t)j*RNK + wid*32 + id]      = (f16)acc0[r];
        o[(size_t)j*RNK + wid*32 + 16 + id] = (f16)acc1[r];
      }
    }
  }
}

// ---------------- gateup MFMA: inter(x256) = silu(h2g@UoG^T /4096)*(h2u@UoU^T /4096)*256 ----------------
__global__ __launch_bounds__(256) void k_mm_gateup(
    const f16* __restrict__ Ag, const f16* __restrict__ Au,
    const f16* __restrict__ Bg, const f16* __restrict__ Bu,
    const int* __restrict__ tg,
    f16* __restrict__ inter){
  const int g = tg[blockIdx.x];
  if(g < 0) return;
  const int j0 = blockIdx.x*32, n0 = blockIdx.y*128;
  const int tid = threadIdx.x;
  const int wid = tid>>6, lane = tid&63, q = lane>>4, id = lane&15;
  const int r0 = j0 + (wid&1)*16;
  const int c0 = n0 + (wid>>1)*64;
  const size_t bbase = (size_t)g*IDIM*RNK;
  f32x4 accg[4], accu[4];
  #pragma unroll
  for(int c = 0; c < 4; c++){ accg[c] = (f32x4){0.f,0.f,0.f,0.f}; accu[c] = (f32x4){0.f,0.f,0.f,0.f}; }
  #pragma unroll 2
  for(int kk = 0; kk < RNK; kk += 32){
    const size_t aoff = (size_t)(r0+id)*RNK + kk + q*8;
    f16x8 ag = ldh8(Ag + aoff);
    f16x8 au = ldh8(Au + aoff);
    #pragma unroll
    for(int c = 0; c < 4; c++){
      const size_t boff = bbase + (size_t)(c0 + c*16 + id)*RNK + kk + q*8;
      f16x8 bg = ldh8(Bg + boff);
      f16x8 bu = ldh8(Bu + boff);
      accg[c] = MFMA16(ag, bg, accg[c]);
      accu[c] = MFMA16(au, bu, accu[c]);
    }
  }
  #pragma unroll
  for(int c = 0; c < 4; c++)
    #pragma unroll
    for(int r = 0; r < 4; r++){
      float vg = accg[c][r] * (1.f/4096.f);
      float vu = accu[c][r] * (1.f/4096.f);
      float sv = vg/(1.f+expf(-vg))*vu*256.f;
      inter[(size_t)(r0 + q*4 + r)*IDIM + c0 + c*16 + id] = (f16)sv;
    }
}

// ---------------- down_in MFMA: d1(x4096) = inter(x256) @ Uid^T(x16) ----------------
// grid (MAXTILES, 4): y&1 = 16-row half, y>>1 = 64-col half; wave = 16 cols
__global__ __launch_bounds__(256) void k_mm_down_in(
    const f16* __restrict__ A_, const f16* __restrict__ B_,
    const int* __restrict__ tg,
    f16* __restrict__ d1){
  const int g = tg[blockIdx.x];
  if(g < 0) return;
  const int j0 = blockIdx.x*32 + (blockIdx.y & 1)*16;
  const int c0 = (blockIdx.y >> 1)*64;
  const f16* B = B_ + (size_t)g*RNK*IDIM;
  const int tid = threadIdx.x;
  const int wid = tid>>6, lane = tid&63, q = lane>>4, id = lane&15;
  const int col0 = c0 + wid*16;
  f32x4 acc = (f32x4){0.f,0.f,0.f,0.f};
  #pragma unroll 4
  for(int kk = 0; kk < IDIM; kk += 32){
    f16x8 a = ldh8(A_ + (size_t)(j0+id)*IDIM   + kk + q*8);
    f16x8 b = ldh8(B  + (size_t)(col0+id)*IDIM + kk + q*8);
    acc = MFMA16(a, b, acc);
  }
  #pragma unroll
  for(int r = 0; r < 4; r++)
    d1[(size_t)(j0 + q*4 + r)*RNK + col0 + id] = (f16)acc[r];
}

// ---------------- core_down MFMA: d2(x65536) = d1(x4096) @ Cdt(x16); gathered segment ----------------
__global__ __launch_bounds__(256) void k_core_down(
    const f16* __restrict__ Cd,
    const f16* __restrict__ d1,
    const int* __restrict__ estart, const int* __restrict__ cnt,
    f16* __restrict__ d2){
  const int e = blockIdx.x;
  const int n = cnt[e];
  if(n == 0) return;
  const int j0 = estart[e];
  const f16* C = Cd + (size_t)e*RNK*RNK;
  const int tid = threadIdx.x;
  const int wid = tid>>6, lane = tid&63, q = lane>>4, id = lane&15;
  for(int rt = 0; rt*16 < n; rt++){
    const int jrow = j0 + rt*16 + id;
    const int jj = jrow < j0+n ? jrow : j0;
    const f16* arow = d1 + (size_t)jj*RNK;
    f32x4 acc0 = (f32x4){0.f,0.f,0.f,0.f};
    f32x4 acc1 = (f32x4){0.f,0.f,0.f,0.f};
    #pragma unroll
    for(int kk = 0; kk < RNK; kk += 32){
      f16x8 a = ldh8(arow + kk + q*8);
      f16x8 b0 = ldh8(C + (size_t)(wid*32 + id)*RNK      + kk + q*8);
      f16x8 b1 = ldh8(C + (size_t)(wid*32 + 16 + id)*RNK + kk + q*8);
      acc0 = MFMA16(a, b0, acc0);
      acc1 = MFMA16(a, b1, acc1);
    }
    #pragma unroll
    for(int r = 0; r < 4; r++){
      const int j = j0 + rt*16 + q*4 + r;
      if(j < j0+n){
        d2[(size_t)j*RNK + wid*32 + id]      = (f16)acc0[r];
        d2[(size_t)j*RNK + wid*32 + 16 + id] = (f16)acc1[r];
      }
    }
  }
}

// ---------------- down_out MFMA: downo = d2(x65536) @ Uod^T(x16) / 2^20 ----------------
__global__ __launch_bounds__(256) void k_mm_down_out(
    const f16* __restrict__ A_, const f16* __restrict__ B_,
    const int* __restrict__ tg,
    float* __restrict__ downo){
  const int g = tg[blockIdx.x];
  if(g < 0) return;
  const int j0 = blockIdx.x*32, n0 = blockIdx.y*128;
  const f16* B = B_ + (size_t)g*HID*RNK;
  const int tid = threadIdx.x;
  const int wid = tid>>6, lane = tid&63, q = lane>>4, id = lane&15;
  const int r0 = j0 + (wid&1)*16;
  const int c0 = n0 + (wid>>1)*64;
  f32x4 acc[4];
  #pragma unroll
  for(int c = 0; c < 4; c++) acc[c] = (f32x4){0.f,0.f,0.f,0.f};
  #pragma unroll 2
  for(int kk = 0; kk < RNK; kk += 32){
    f16x8 a = ldh8(A_ + (size_t)(r0+id)*RNK + kk + q*8);
    #pragma unroll
    for(int c = 0; c < 4; c++){
      f16x8 b = ldh8(B + (size_t)(c0 + c*16 + id)*RNK + kk + q*8);
      acc[c] = MFMA16(a, b, acc[c]);
    }
  }
  #pragma unroll
  for(int c = 0; c < 4; c++)
    #pragma unroll
    for(int r = 0; r < 4; r++)
      downo[(size_t)(r0 + q*4 + r)*HID + c0 + c*16 + id] = acc[c][r]*(1.f/1048576.f);
}

// ---------------- combine: out[t] = sum_k wt * downo[pos(t,k)] ----------------
__global__ __launch_bounds__(256) void k_combine(const float* __restrict__ downo,
                                                 const int* __restrict__ pos_of_pair,
                                                 const float* __restrict__ wt,
                                                 float* __restrict__ out){
  const int idx = blockIdx.x*256 + threadIdx.x;      // 0..262143
  const int t  = idx >> 9;
  const int h4 = (idx & 511) << 2;
  float4 acc = make_float4(0.f,0.f,0.f,0.f);
  #pragma unroll
  for(int k = 0; k < KTOP; k++){
    const int p = t*KTOP + k;
    const float w = wt[p];
    const int pos = pos_of_pair[p];
    float4 v = ld4(&downo[(size_t)pos*HID + h4]);
    acc.x += w*v.x; acc.y += w*v.y; acc.z += w*v.z; acc.w += w*v.w;
  }
  st4(&out[(size_t)t*HID + h4], acc);
}

extern "C" void kernel_launch(void* const* d_in, const int* in_sizes, int n_in,
                              void* d_out, int out_size, void* d_ws, size_t ws_size,
                              hipStream_t stream){
  const float* x   = (const float*)d_in[0];
  const float* wr  = (const float*)d_in[1];
  const float* Uig = (const float*)d_in[2];
  const float* cg  = (const float*)d_in[3];
  const float* Uog = (const float*)d_in[4];
  const float* Uiu = (const float*)d_in[5];
  const float* cu  = (const float*)d_in[6];
  const float* Uou = (const float*)d_in[7];
  const float* Uid = (const float*)d_in[8];
  const float* cd  = (const float*)d_in[9];
  const float* Uod = (const float*)d_in[10];
  float* out = (float*)d_out;
  char* ws = (char*)d_ws;
  if(ws_size < WS_NEED) return;   // insufficient scratch — fail visibly

  int*   sel    = (int*)  (ws + OFF_SEL);
  float* wt     = (float*)(ws + OFF_WT);
  int*   cnt    = (int*)  (ws + OFF_CNT);
  int*   estart = (int*)  (ws + OFF_ESTART);
  int*   ecur   = (int*)  (ws + OFF_ECUR);
  int*   tg     = (int*)  (ws + OFF_TG);
  int*   hdr    = (int*)  (ws + OFF_HDR);
  int*   row_t  = (int*)  (ws + OFF_ROWT);
  int*   pos    = (int*)  (ws + OFF_POS);
  float* lpart  = (float*)(ws + OFF_LPART);
  f16* xh    = (f16*)(ws + OFF_XH);
  f16* utig  = (f16*)(ws + OFF_UTIG);
  f16* utiu  = (f16*)(ws + OFF_UTIU);
  f16* cgt   = (f16*)(ws + OFF_CGT);
  f16* cut   = (f16*)(ws + OFF_CUT);
  f16* cdt   = (f16*)(ws + OFF_CDT);
  f16* H1    = (f16*)(ws + OFF_H1);
  f16* uog   = (f16*)(ws + OFF_UOG);
  f16* uou   = (f16*)(ws + OFF_UOU);
  f16* utid  = (f16*)(ws + OFF_UTID);
  f16* uod   = (f16*)(ws + OFF_UOD);
  f16* h2g   = (f16*)(ws + OFF_H2G);
  f16* h2u   = (f16*)(ws + OFF_H2U);
  f16* inter = (f16*)(ws + OFF_INTER);
  f16* d1    = (f16*)(ws + OFF_D1);
  f16* d2    = (f16*)(ws + OFF_D2);
  float* downo = (float*)(ws + OFF_DOWNO);

  hipMemsetAsync(cnt, 0, NEXP*sizeof(int), stream);

  // routing chain (lpart overlays H1, dead before stage1)
  k_router4  <<<dim3(16,4,4),      256, 0, stream>>>(x, wr, lpart);
  k_topk     <<<TNUM,              256, 0, stream>>>(lpart, sel, wt, cnt);
  k_meta     <<<1,                 256, 0, stream>>>(cnt, estart, ecur, tg, hdr);
  k_scatter  <<<12,                256, 0, stream>>>(sel, ecur, row_t, pos);

  // conversions (f16, power-of-2 scales; cores transposed)
  k_cvt_all  <<<5888,              256, 0, stream>>>(x, Uog, Uou, Uod, xh, uog, uou, uod);
  k_cvt_t3   <<<dim3(4,64,24),     256, 0, stream>>>(Uig, Uiu, Uid, utig, utiu, utid);
  k_cvt_core <<<dim3(4,4,768),     256, 0, stream>>>(cg, cu, cd, cgt, cut, cdt);

  k_mm_stage1<<<dim3(16,8,8),      256, 0, stream>>>(xh, utig, utiu, H1);
  k_core2    <<<dim3(NEXP,2),      256, 0, stream>>>(cgt, cut, H1, estart, cnt, row_t, h2g, h2u);
  k_mm_gateup<<<dim3(MAXTILES,11), 256, 0, stream>>>(h2g, h2u, uog, uou, tg, inter);
  k_mm_down_in<<<dim3(MAXTILES,4), 256, 0, stream>>>(inter, utid, tg, d1);
  k_core_down<<<NEXP,              256, 0, stream>>>(cdt, d1, estart, cnt, d2);
  k_mm_down_out<<<dim3(MAXTILES,16),256,0, stream>>>(d2, uod, tg, downo);
  k_combine  <<<1024,              256, 0, stream>>>(downo, pos, wt, out);
}

// Round 6
// 155.734 us; speedup vs baseline: 3.2506x; 1.3373x over previous
//
#include <hip/hip_runtime.h>
#include <cmath>
#include <cstdint>

#define TNUM 512
#define HID 2048
#define NEXP 256
#define NGRP 8
#define KTOP 6
#define IDIM 1408
#define RNK 128
#define NPAIR (TNUM*KTOP)          // 3072
#define NRCAP 3328                 // 3072 + 8*32 padding capacity
#define MAXTILES (NRCAP/32)        // 104

typedef _Float16 f16;
typedef f16  f16x8 __attribute__((ext_vector_type(8)));
typedef f16  f16x4 __attribute__((ext_vector_type(4)));
typedef float f32x4 __attribute__((ext_vector_type(4)));
#define MFMA16(a,b,c) __builtin_amdgcn_mfma_f32_16x16x32_f16((a),(b),(c),0,0,0)

static __device__ __forceinline__ float4 ld4(const float* p){ return *reinterpret_cast<const float4*>(p); }
static __device__ __forceinline__ void st4(float* p, float4 v){ *reinterpret_cast<float4*>(p) = v; }
static __device__ __forceinline__ f16x8 ldh8(const f16* p){ return *reinterpret_cast<const f16x8*>(p); }

// ---------------- workspace layout (~54 MB with overlays) ----------------
constexpr size_t A256(size_t x){ return (x + 255) & ~(size_t)255; }
constexpr size_t OFF_SEL    = 0;
constexpr size_t OFF_WT     = A256(OFF_SEL    + (size_t)NPAIR*4);
constexpr size_t OFF_CNT    = A256(OFF_WT     + (size_t)NPAIR*4);
constexpr size_t OFF_ESTART = A256(OFF_CNT    + (size_t)NEXP*4);
constexpr size_t OFF_ECUR   = A256(OFF_ESTART + (size_t)NEXP*4);
constexpr size_t OFF_TG     = A256(OFF_ECUR   + (size_t)NEXP*4);
constexpr size_t OFF_HDR    = A256(OFF_TG     + (size_t)MAXTILES*4);
constexpr size_t OFF_ROWT   = A256(OFF_HDR    + 16);
constexpr size_t OFF_POS    = A256(OFF_ROWT   + (size_t)NRCAP*4);
constexpr size_t OFF_BIG    = A256(OFF_POS    + (size_t)NPAIR*4);

constexpr size_t SZ_XH    = (size_t)TNUM*HID*2;            // 2 MB
constexpr size_t SZ_UTI   = (size_t)NGRP*RNK*HID*2;        // 4 MB
constexpr size_t SZ_CT    = (size_t)NEXP*RNK*RNK*2;        // 8 MB
constexpr size_t SZ_H1ALL = (size_t)2*TNUM*NGRP*RNK*2;     // 2 MB (pu planes, f16)
constexpr size_t SZ_UO    = (size_t)NGRP*IDIM*RNK*2;       // 2.88 MB
constexpr size_t SZ_UOD   = (size_t)NGRP*HID*RNK*2;        // 4 MB
constexpr size_t SZ_H2    = (size_t)NRCAP*RNK*2;           // 0.85 MB
constexpr size_t SZ_INTER = (size_t)NRCAP*IDIM*2;          // 9.37 MB
constexpr size_t SZ_DOWNO = (size_t)NRCAP*HID*4;           // 27.26 MB

// overlay region: [xh|utig|utiu|cgt|cut|H1] = 28 MB; downo overlays whole; inter overlays first 10 MB
constexpr size_t OFF_XH    = OFF_BIG;
constexpr size_t OFF_UTIG  = OFF_XH   + SZ_XH;
constexpr size_t OFF_UTIU  = OFF_UTIG + SZ_UTI;
constexpr size_t OFF_CGT   = OFF_UTIU + SZ_UTI;
constexpr size_t OFF_CUT   = OFF_CGT  + SZ_CT;
constexpr size_t OFF_H1    = OFF_CUT  + SZ_CT;             // f16 [2][T][G*RNK]
constexpr size_t REG_END   = OFF_H1   + SZ_H1ALL;
constexpr size_t OFF_INTER = OFF_XH;                       // lives gateup->down_in
constexpr size_t OFF_DOWNO = OFF_XH;                       // lives down_out->combine
constexpr size_t OFF_LPART = OFF_H1;                       // 2 MB, dead before stage1
// persistent tail
constexpr size_t OFF_UOG   = REG_END;
constexpr size_t OFF_UOU   = OFF_UOG  + SZ_UO;
constexpr size_t OFF_UTID  = OFF_UOU  + SZ_UO;
constexpr size_t OFF_UOD   = OFF_UTID + SZ_UO;
constexpr size_t OFF_CDT   = OFF_UOD  + SZ_UOD;
constexpr size_t OFF_H2G   = OFF_CDT  + SZ_CT;
constexpr size_t OFF_H2U   = OFF_H2G  + SZ_H2;
constexpr size_t OFF_D1    = OFF_H2U  + SZ_H2;
constexpr size_t OFF_D2    = OFF_D1   + SZ_H2;
constexpr size_t WS_NEED   = OFF_D2   + SZ_H2;             // ~54.1 MB
static_assert(OFF_DOWNO + SZ_DOWNO <= OFF_UOG, "downo overlay must end before persistent tail");
static_assert(OFF_INTER + SZ_INTER <= OFF_CGT, "inter overlay must end before cores");

// ---------------- merged fp32 -> f16 converter (x, Uog, Uou, Uod) ----------------
__global__ __launch_bounds__(256) void k_cvt_all(
    const float* __restrict__ x,   const float* __restrict__ Uog,
    const float* __restrict__ Uou, const float* __restrict__ Uod,
    f16* __restrict__ xh, f16* __restrict__ uog, f16* __restrict__ uou, f16* __restrict__ uod){
  const int b = blockIdx.x, tid = threadIdx.x;
  const float* in; f16* hi; size_t i; float scale;
  if(b < 1024){        in = x;   hi = xh;  i = (size_t)b*256 + tid;        scale = 1.f; }
  else if(b < 2432){   in = Uog; hi = uog; i = (size_t)(b-1024)*256 + tid; scale = 16.f; }
  else if(b < 3840){   in = Uou; hi = uou; i = (size_t)(b-2432)*256 + tid; scale = 16.f; }
  else {               in = Uod; hi = uod; i = (size_t)(b-3840)*256 + tid; scale = 16.f; }
  float4 v = ld4(in + i*4);
  f16x4 H;
  H[0]=(f16)(v.x*scale); H[1]=(f16)(v.y*scale); H[2]=(f16)(v.z*scale); H[3]=(f16)(v.w*scale);
  *reinterpret_cast<f16x4*>(hi + i*4) = H;
}

// merged transpose-convert: Uig/Uiu (R=2048) + Uid (R=1408): [G][R][128] -> [G][128][R] (x16)
__global__ __launch_bounds__(256) void k_cvt_t3(
    const float* __restrict__ Uig, const float* __restrict__ Uiu, const float* __restrict__ Uid,
    f16* __restrict__ ig, f16* __restrict__ iu, f16* __restrict__ idn){
  __shared__ float tile[32][33];
  const int z = blockIdx.z, tensor = z>>3, g = z&7;
  const float* in; f16* hi; int R;
  if(tensor == 0){ in = Uig; hi = ig; R = HID; }
  else if(tensor == 1){ in = Uiu; hi = iu; R = HID; }
  else { in = Uid; hi = idn; R = IDIM; }
  const int r0 = blockIdx.y*32, c0 = blockIdx.x*32;
  if(r0 >= R) return;
  const int tid = threadIdx.x;
  { const int r = tid>>3, c4 = (tid&7)*4;
    float4 v = ld4(in + ((size_t)g*R + r0 + r)*RNK + c0 + c4);
    tile[r][c4]=v.x; tile[r][c4+1]=v.y; tile[r][c4+2]=v.z; tile[r][c4+3]=v.w; }
  __syncthreads();
  { const int c = tid>>3, r4 = (tid&7)*4;
    f16x4 H;
    #pragma unroll
    for(int k = 0; k < 4; k++) H[k] = (f16)(tile[r4+k][c]*16.f);
    *reinterpret_cast<f16x4*>(hi + ((size_t)g*RNK + c0 + c)*R + r0 + r4) = H; }
}

// core transpose-convert: [E][r1][r2] -> f16 [E][r2][r1] (x16); grid (4,4,3*256)
__global__ __launch_bounds__(256) void k_cvt_core(
    const float* __restrict__ cg, const float* __restrict__ cu, const float* __restrict__ cd,
    f16* __restrict__ cgt, f16* __restrict__ cut, f16* __restrict__ cdt){
  __shared__ float tile[32][33];
  const int z = blockIdx.z, tensor = z>>8, e = z&255;
  const float* in; f16* o;
  if(tensor == 0){ in = cg; o = cgt; }
  else if(tensor == 1){ in = cu; o = cut; }
  else { in = cd; o = cdt; }
  in += (size_t)e*RNK*RNK; o += (size_t)e*RNK*RNK;
  const int r0 = blockIdx.y*32, c0 = blockIdx.x*32;
  const int tid = threadIdx.x;
  { const int r = tid>>3, c4 = (tid&7)*4;
    float4 v = ld4(in + (size_t)(r0+r)*RNK + c0 + c4);
    tile[r][c4]=v.x; tile[r][c4+1]=v.y; tile[r][c4+2]=v.z; tile[r][c4+3]=v.w; }
  __syncthreads();
  { const int c = tid>>3, r4 = (tid&7)*4;
    f16x4 H;
    #pragma unroll
    for(int k = 0; k < 4; k++) H[k] = (f16)(tile[r4+k][c]*16.f);
    *reinterpret_cast<f16x4*>(o + (size_t)(c0+c)*RNK + r0 + r4) = H; }
}

// ---------------- router GEMM, K-split x4 (fp32, selection-critical) ----------------
__global__ __launch_bounds__(256) void k_router4(const float* __restrict__ x,
                                                 const float* __restrict__ w,
                                                 float* __restrict__ lpart){
  __shared__ float As[32][68];
  __shared__ float Bs[64][64];
  const int tid = threadIdx.x;
  const int t0 = blockIdx.x*32, e0 = blockIdx.y*64, kz = blockIdx.z;
  const int kb = kz*512;
  const int tx = tid & 15, ty = tid >> 4;
  float acc[2][4] = {{0.f}};
  for(int kc = 0; kc < 512; kc += 64){
    { const int r = tid>>3, k4 = (tid&7)<<2;
      st4(&As[r][k4],      ld4(&x[(size_t)(t0+r)*HID + kb + kc + k4]));
      st4(&As[r][k4+32],   ld4(&x[(size_t)(t0+r)*HID + kb + kc + k4 + 32])); }
    #pragma unroll
    for(int i = 0; i < 4; i++){ int idx = tid + i*256; int kr = idx>>4, e4 = (idx&15)<<2;
      st4(&Bs[kr][e4], ld4(&w[(size_t)(kb+kc+kr)*NEXP + e0 + e4])); }
    __syncthreads();
    for(int kk = 0; kk < 64; kk++){
      float4 b = ld4(&Bs[kk][tx<<2]);
      float a0 = As[(ty<<1)][kk], a1 = As[(ty<<1)+1][kk];
      acc[0][0] += a0*b.x; acc[0][1] += a0*b.y; acc[0][2] += a0*b.z; acc[0][3] += a0*b.w;
      acc[1][0] += a1*b.x; acc[1][1] += a1*b.y; acc[1][2] += a1*b.z; acc[1][3] += a1*b.w;
    }
    __syncthreads();
  }
  #pragma unroll
  for(int r = 0; r < 2; r++)
    st4(&lpart[((size_t)kz*TNUM + t0 + (ty<<1) + r)*NEXP + e0 + (tx<<2)],
        make_float4(acc[r][0],acc[r][1],acc[r][2],acc[r][3]));
}

// ---------------- per-token top-6 (wave-parallel argmax) ----------------
__global__ __launch_bounds__(256) void k_topk(const float* __restrict__ lpart,
                                              int* __restrict__ sel,
                                              float* __restrict__ wt,
                                              int* __restrict__ cnt){
  __shared__ float wv[4];
  __shared__ int   wi[4];
  __shared__ float swin[KTOP];
  __shared__ int   iwin[KTOP];
  const int t = blockIdx.x, tid = threadIdx.x;
  const int lane = tid & 63, wid = tid >> 6;
  const size_t base = (size_t)t*NEXP + tid;
  float v = lpart[base] + lpart[base + (size_t)TNUM*NEXP]
          + lpart[base + (size_t)2*TNUM*NEXP] + lpart[base + (size_t)3*TNUM*NEXP];
  for(int k = 0; k < KTOP; k++){
    float cv = v; int ci = tid;
    #pragma unroll
    for(int off = 1; off < 64; off <<= 1){
      float ov = __shfl_xor(cv, off);
      int   oi = __shfl_xor(ci, off);
      if(ov > cv || (ov == cv && oi < ci)){ cv = ov; ci = oi; }
    }
    if(lane == 0){ wv[wid] = cv; wi[wid] = ci; }
    __syncthreads();
    if(tid == 0){
      float bv = wv[0]; int bi = wi[0];
      #pragma unroll
      for(int w2 = 1; w2 < 4; w2++)
        if(wv[w2] > bv || (wv[w2] == bv && wi[w2] < bi)){ bv = wv[w2]; bi = wi[w2]; }
      swin[k] = bv; iwin[k] = bi;
    }
    __syncthreads();
    if(tid == iwin[k]) v = -INFINITY;
  }
  if(tid == 0){
    float mx = swin[0], s = 0.f, ww[KTOP];
    #pragma unroll
    for(int k = 0; k < KTOP; k++){ ww[k] = expf(swin[k]-mx); s += ww[k]; }
    float inv = 1.f/s;
    #pragma unroll
    for(int k = 0; k < KTOP; k++){
      sel[t*KTOP+k] = iwin[k];
      wt[t*KTOP+k]  = ww[k]*inv;
      atomicAdd(&cnt[iwin[k]], 1);
    }
  }
}

// ---------------- offsets / padded segments / tile->group ----------------
__global__ __launch_bounds__(256) void k_meta(const int* __restrict__ cnt,
                                              int* __restrict__ estart,
                                              int* __restrict__ ecursor,
                                              int* __restrict__ tile_group,
                                              int* __restrict__ hdr){
  __shared__ int scnt[256];
  __shared__ int gsum[8];
  __shared__ int g0[9];
  const int tid = threadIdx.x;
  scnt[tid] = cnt[tid];
  if(tid < 8) gsum[tid] = 0;
  __syncthreads();
  atomicAdd(&gsum[tid>>5], scnt[tid]);
  __syncthreads();
  if(tid == 0){
    int run = 0;
    for(int g = 0; g < 8; g++){ g0[g] = run; run += (gsum[g]+31) & ~31; }
    g0[8] = run; hdr[0] = run>>5; hdr[1] = run;
  }
  __syncthreads();
  int g = tid >> 5, s = g0[g];
  for(int i = (g<<5); i < tid; i++) s += scnt[i];
  estart[tid] = s; ecursor[tid] = s;
  const int nt = g0[8] >> 5;
  for(int t2 = tid; t2 < MAXTILES; t2 += 256){
    int gg = -1;
    if(t2 < nt){
      for(int g2 = 0; g2 < 8; g2++) if(t2*32 >= g0[g2] && t2*32 < g0[g2+1]) gg = g2;
    }
    tile_group[t2] = gg;
  }
}

// ---------------- scatter pairs into sorted rows ----------------
__global__ __launch_bounds__(256) void k_scatter(const int* __restrict__ sel,
                                                 int* __restrict__ ecursor,
                                                 int* __restrict__ row_t,
                                                 int* __restrict__ pos_of_pair){
  const int p = blockIdx.x*256 + threadIdx.x;
  if(p >= NPAIR) return;
  const int e = sel[p];
  const int pos = atomicAdd(&ecursor[e], 1);
  row_t[pos] = p / KTOP;
  pos_of_pair[p] = pos;
}

// ---------------- stage1 MFMA v3: in-block K-split, 32x64 tile, LDS reduce ----------------
// grid (16, 32): nt -> pu=nt>>4, g=(nt>>1)&7, ch=nt&1; 4 waves each own K-quarter (512)
__global__ __launch_bounds__(256) void k_mm_stage1(
    const f16* __restrict__ xh,
    const f16* __restrict__ Bg_, const f16* __restrict__ Bu_,
    f16* __restrict__ H1){
  __shared__ float red[4][32][64];
  const int m = blockIdx.x, nt = blockIdx.y;
  const int pu = nt>>4, g = (nt>>1)&7, ch = nt&1;
  const f16* B = (pu ? Bu_ : Bg_) + (size_t)g*RNK*HID + (size_t)ch*64*HID;
  const int tid = threadIdx.x;
  const int wid = tid>>6, lane = tid&63, q = lane>>4, id = lane&15;
  const int kb = wid*512;
  const int r0 = m*32;
  f32x4 acc[2][4];
  #pragma unroll
  for(int f = 0; f < 2; f++)
    #pragma unroll
    for(int c = 0; c < 4; c++) acc[f][c] = (f32x4){0.f,0.f,0.f,0.f};
  #pragma unroll 4
  for(int kk = 0; kk < 512; kk += 32){
    f16x8 a0 = ldh8(xh + (size_t)(r0+id)*HID    + kb + kk + q*8);
    f16x8 a1 = ldh8(xh + (size_t)(r0+16+id)*HID + kb + kk + q*8);
    #pragma unroll
    for(int c = 0; c < 4; c++){
      f16x8 b = ldh8(B + (size_t)(c*16+id)*HID + kb + kk + q*8);
      acc[0][c] = MFMA16(a0, b, acc[0][c]);
      acc[1][c] = MFMA16(a1, b, acc[1][c]);
    }
  }
  #pragma unroll
  for(int f = 0; f < 2; f++)
    #pragma unroll
    for(int c = 0; c < 4; c++)
      #pragma unroll
      for(int r = 0; r < 4; r++)
        red[wid][f*16 + q*4 + r][c*16 + id] = acc[f][c][r];
  __syncthreads();
  f16* out = H1 + (size_t)pu*TNUM*(NGRP*RNK);
  const int row = tid>>3, c8 = (tid&7)*8;
  f16x8 o8;
  #pragma unroll
  for(int j = 0; j < 8; j++)
    o8[j] = (f16)(red[0][row][c8+j] + red[1][row][c8+j] + red[2][row][c8+j] + red[3][row][c8+j]);
  *reinterpret_cast<f16x8*>(&out[(size_t)(r0+row)*(NGRP*RNK) + g*RNK + ch*64 + c8]) = o8;
}

// ---------------- core2 MFMA: h2(x256) = H1(x16) @ Ct(x16); gathered rows ----------------
__global__ __launch_bounds__(256) void k_core2(
    const f16* __restrict__ Cg, const f16* __restrict__ Cu,
    const f16* __restrict__ H1,
    const int* __restrict__ estart, const int* __restrict__ cnt,
    const int* __restrict__ row_t,
    f16* __restrict__ h2g, f16* __restrict__ h2u){
  const int e = blockIdx.x, up = blockIdx.y;
  const int n = cnt[e];
  if(n == 0) return;
  const int j0 = estart[e], g = e >> 5;
  const f16* C = (up ? Cu : Cg) + (size_t)e*RNK*RNK;
  const f16* A = H1 + (size_t)up*TNUM*(NGRP*RNK);
  f16* o = up ? h2u : h2g;
  const int tid = threadIdx.x;
  const int wid = tid>>6, lane = tid&63, q = lane>>4, id = lane&15;
  for(int rt = 0; rt*16 < n; rt++){
    const int jrow = j0 + rt*16 + id;
    const int jj = jrow < j0+n ? jrow : j0;
    const f16* arow = A + (size_t)row_t[jj]*(NGRP*RNK) + g*RNK;
    f32x4 acc0 = (f32x4){0.f,0.f,0.f,0.f};
    f32x4 acc1 = (f32x4){0.f,0.f,0.f,0.f};
    #pragma unroll
    for(int kk = 0; kk < RNK; kk += 32){
      f16x8 a = ldh8(arow + kk + q*8);
      f16x8 b0 = ldh8(C + (size_t)(wid*32 + id)*RNK      + kk + q*8);
      f16x8 b1 = ldh8(C + (size_t)(wid*32 + 16 + id)*RNK + kk + q*8);
      acc0 = MFMA16(a, b0, acc0);
      acc1 = MFMA16(a, b1, acc1);
    }
    #pragma unroll
    for(int r = 0; r < 4; r++){
      const int j = j0 + rt*16 + q*4 + r;
      if(j < j0+n){
        o[(size_t)j*RNK + wid*32 + id]      = (f16)acc0[r];
        o[(size_t)j*RNK + wid*32 + 16 + id] = (f16)acc1[r];
      }
    }
  }
}

// ---------------- gateup MFMA v2: 128 thr / 2 waves, 32 rows x 64 cols per wave, both planes ----------------
// grid (MAXTILES, 11)
__global__ __launch_bounds__(128) void k_mm_gateup(
    const f16* __restrict__ Ag, const f16* __restrict__ Au,
    const f16* __restrict__ Bg, const f16* __restrict__ Bu,
    const int* __restrict__ tg,
    f16* __restrict__ inter){
  const int g = tg[blockIdx.x];
  if(g < 0) return;
  const int j0 = blockIdx.x*32;
  const int tid = threadIdx.x;
  const int wid = tid>>6, lane = tid&63, q = lane>>4, id = lane&15;
  const int c0 = blockIdx.y*128 + wid*64;
  const size_t bbase = (size_t)g*IDIM*RNK;
  f32x4 accg[2][4], accu[2][4];
  #pragma unroll
  for(int f = 0; f < 2; f++)
    #pragma unroll
    for(int c = 0; c < 4; c++){ accg[f][c] = (f32x4){0.f,0.f,0.f,0.f}; accu[f][c] = (f32x4){0.f,0.f,0.f,0.f}; }
  #pragma unroll 2
  for(int kk = 0; kk < RNK; kk += 32){
    const size_t a0off = (size_t)(j0+id)*RNK    + kk + q*8;
    const size_t a1off = (size_t)(j0+16+id)*RNK + kk + q*8;
    f16x8 ag0 = ldh8(Ag + a0off), ag1 = ldh8(Ag + a1off);
    f16x8 au0 = ldh8(Au + a0off), au1 = ldh8(Au + a1off);
    #pragma unroll
    for(int c = 0; c < 4; c++){
      const size_t boff = bbase + (size_t)(c0 + c*16 + id)*RNK + kk + q*8;
      f16x8 bg = ldh8(Bg + boff);
      f16x8 bu = ldh8(Bu + boff);
      accg[0][c] = MFMA16(ag0, bg, accg[0][c]);
      accg[1][c] = MFMA16(ag1, bg, accg[1][c]);
      accu[0][c] = MFMA16(au0, bu, accu[0][c]);
      accu[1][c] = MFMA16(au1, bu, accu[1][c]);
    }
  }
  #pragma unroll
  for(int f = 0; f < 2; f++)
    #pragma unroll
    for(int c = 0; c < 4; c++)
      #pragma unroll
      for(int r = 0; r < 4; r++){
        float vg = accg[f][c][r] * (1.f/4096.f);
        float vu = accu[f][c][r] * (1.f/4096.f);
        float sv = vg/(1.f+expf(-vg))*vu*256.f;
        inter[(size_t)(j0 + f*16 + q*4 + r)*IDIM + c0 + c*16 + id] = (f16)sv;
      }
}

// ---------------- down_in MFMA v3: in-block K-split (4x352), 32x64 tile, LDS reduce ----------------
// grid (MAXTILES, 2): ch = col half
__global__ __launch_bounds__(256) void k_mm_down_in(
    const f16* __restrict__ A_, const f16* __restrict__ B_,
    const int* __restrict__ tg,
    f16* __restrict__ d1){
  __shared__ float red[4][32][64];
  const int g = tg[blockIdx.x];
  if(g < 0) return;
  const int j0 = blockIdx.x*32;
  const int ch = blockIdx.y;
  const f16* B = B_ + (size_t)g*RNK*IDIM + (size_t)ch*64*IDIM;
  const int tid = threadIdx.x;
  const int wid = tid>>6, lane = tid&63, q = lane>>4, id = lane&15;
  const int kb = wid*352;
  f32x4 acc[2][4];
  #pragma unroll
  for(int f = 0; f < 2; f++)
    #pragma unroll
    for(int c = 0; c < 4; c++) acc[f][c] = (f32x4){0.f,0.f,0.f,0.f};
  #pragma unroll 2
  for(int kk = 0; kk < 352; kk += 32){
    f16x8 a0 = ldh8(A_ + (size_t)(j0+id)*IDIM    + kb + kk + q*8);
    f16x8 a1 = ldh8(A_ + (size_t)(j0+16+id)*IDIM + kb + kk + q*8);
    #pragma unroll
    for(int c = 0; c < 4; c++){
      f16x8 b = ldh8(B + (size_t)(c*16+id)*IDIM + kb + kk + q*8);
      acc[0][c] = MFMA16(a0, b, acc[0][c]);
      acc[1][c] = MFMA16(a1, b, acc[1][c]);
    }
  }
  #pragma unroll
  for(int f = 0; f < 2; f++)
    #pragma unroll
    for(int c = 0; c < 4; c++)
      #pragma unroll
      for(int r = 0; r < 4; r++)
        red[wid][f*16 + q*4 + r][c*16 + id] = acc[f][c][r];
  __syncthreads();
  const int row = tid>>3, c8 = (tid&7)*8;
  f16x8 o8;
  #pragma unroll
  for(int j = 0; j < 8; j++)
    o8[j] = (f16)(red[0][row][c8+j] + red[1][row][c8+j] + red[2][row][c8+j] + red[3][row][c8+j]);
  *reinterpret_cast<f16x8*>(&d1[(size_t)(j0+row)*RNK + ch*64 + c8]) = o8;
}

// ---------------- core_down MFMA: d2(x65536) = d1(x4096) @ Cdt(x16); gathered segment ----------------
__global__ __launch_bounds__(256) void k_core_down(
    const f16* __restrict__ Cd,
    const f16* __restrict__ d1,
    const int* __restrict__ estart, const int* __restrict__ cnt,
    f16* __restrict__ d2){
  const int e = blockIdx.x;
  const int n = cnt[e];
  if(n == 0) return;
  const int j0 = estart[e];
  const f16* C = Cd + (size_t)e*RNK*RNK;
  const int tid = threadIdx.x;
  const int wid = tid>>6, lane = tid&63, q = lane>>4, id = lane&15;
  for(int rt = 0; rt*16 < n; rt++){
    const int jrow = j0 + rt*16 + id;
    const int jj = jrow < j0+n ? jrow : j0;
    const f16* arow = d1 + (size_t)jj*RNK;
    f32x4 acc0 = (f32x4){0.f,0.f,0.f,0.f};
    f32x4 acc1 = (f32x4){0.f,0.f,0.f,0.f};
    #pragma unroll
    for(int kk = 0; kk < RNK; kk += 32){
      f16x8 a = ldh8(arow + kk + q*8);
      f16x8 b0 = ldh8(C + (size_t)(wid*32 + id)*RNK      + kk + q*8);
      f16x8 b1 = ldh8(C + (size_t)(wid*32 + 16 + id)*RNK + kk + q*8);
      acc0 = MFMA16(a, b0, acc0);
      acc1 = MFMA16(a, b1, acc1);
    }
    #pragma unroll
    for(int r = 0; r < 4; r++){
      const int j = j0 + rt*16 + q*4 + r;
      if(j < j0+n){
        d2[(size_t)j*RNK + wid*32 + id]      = (f16)acc0[r];
        d2[(size_t)j*RNK + wid*32 + 16 + id] = (f16)acc1[r];
      }
    }
  }
}

// ---------------- down_out MFMA v2: 128 thr / 2 waves, 32 rows x 64 cols per wave ----------------
// grid (MAXTILES, 16)
__global__ __launch_bounds__(128) void k_mm_down_out(
    const f16* __restrict__ A_, const f16* __restrict__ B_,
    const int* __restrict__ tg,
    float* __restrict__ downo){
  const int g = tg[blockIdx.x];
  if(g < 0) return;
  const int j0 = blockIdx.x*32;
  const f16* B = B_ + (size_t)g*HID*RNK;
  const int tid = threadIdx.x;
  const int wid = tid>>6, lane = tid&63, q = lane>>4, id = lane&15;
  const int c0 = blockIdx.y*128 + wid*64;
  f32x4 acc[2][4];
  #pragma unroll
  for(int f = 0; f < 2; f++)
    #pragma unroll
    for(int c = 0; c < 4; c++) acc[f][c] = (f32x4){0.f,0.f,0.f,0.f};
  #pragma unroll 2
  for(int kk = 0; kk < RNK; kk += 32){
    f16x8 a0 = ldh8(A_ + (size_t)(j0+id)*RNK    + kk + q*8);
    f16x8 a1 = ldh8(A_ + (size_t)(j0+16+id)*RNK + kk + q*8);
    #pragma unroll
    for(int c = 0; c < 4; c++){
      f16x8 b = ldh8(B + (size_t)(c0 + c*16 + id)*RNK + kk + q*8);
      acc[0][c] = MFMA16(a0, b, acc[0][c]);
      acc[1][c] = MFMA16(a1, b, acc[1][c]);
    }
  }
  #pragma unroll
  for(int f = 0; f < 2; f++)
    #pragma unroll
    for(int c = 0; c < 4; c++)
      #pragma unroll
      for(int r = 0; r < 4; r++)
        downo[(size_t)(j0 + f*16 + q*4 + r)*HID + c0 + c*16 + id] = acc[f][c][r]*(1.f/1048576.f);
}

// ---------------- combine: out[t] = sum_k wt * downo[pos(t,k)] ----------------
__global__ __launch_bounds__(256) void k_combine(const float* __restrict__ downo,
                                                 const int* __restrict__ pos_of_pair,
                                                 const float* __restrict__ wt,
                                                 float* __restrict__ out){
  const int idx = blockIdx.x*256 + threadIdx.x;      // 0..262143
  const int t  = idx >> 9;
  const int h4 = (idx & 511) << 2;
  float4 acc = make_float4(0.f,0.f,0.f,0.f);
  #pragma unroll
  for(int k = 0; k < KTOP; k++){
    const int p = t*KTOP + k;
    const float w = wt[p];
    const int pos = pos_of_pair[p];
    float4 v = ld4(&downo[(size_t)pos*HID + h4]);
    acc.x += w*v.x; acc.y += w*v.y; acc.z += w*v.z; acc.w += w*v.w;
  }
  st4(&out[(size_t)t*HID + h4], acc);
}

extern "C" void kernel_launch(void* const* d_in, const int* in_sizes, int n_in,
                              void* d_out, int out_size, void* d_ws, size_t ws_size,
                              hipStream_t stream){
  const float* x   = (const float*)d_in[0];
  const float* wr  = (const float*)d_in[1];
  const float* Uig = (const float*)d_in[2];
  const float* cg  = (const float*)d_in[3];
  const float* Uog = (const float*)d_in[4];
  const float* Uiu = (const float*)d_in[5];
  const float* cu  = (const float*)d_in[6];
  const float* Uou = (const float*)d_in[7];
  const float* Uid = (const float*)d_in[8];
  const float* cd  = (const float*)d_in[9];
  const float* Uod = (const float*)d_in[10];
  float* out = (float*)d_out;
  char* ws = (char*)d_ws;
  if(ws_size < WS_NEED) return;   // insufficient scratch — fail visibly

  int*   sel    = (int*)  (ws + OFF_SEL);
  float* wt     = (float*)(ws + OFF_WT);
  int*   cnt    = (int*)  (ws + OFF_CNT);
  int*   estart = (int*)  (ws + OFF_ESTART);
  int*   ecur   = (int*)  (ws + OFF_ECUR);
  int*   tg     = (int*)  (ws + OFF_TG);
  int*   hdr    = (int*)  (ws + OFF_HDR);
  int*   row_t  = (int*)  (ws + OFF_ROWT);
  int*   pos    = (int*)  (ws + OFF_POS);
  float* lpart  = (float*)(ws + OFF_LPART);
  f16* xh    = (f16*)(ws + OFF_XH);
  f16* utig  = (f16*)(ws + OFF_UTIG);
  f16* utiu  = (f16*)(ws + OFF_UTIU);
  f16* cgt   = (f16*)(ws + OFF_CGT);
  f16* cut   = (f16*)(ws + OFF_CUT);
  f16* cdt   = (f16*)(ws + OFF_CDT);
  f16* H1    = (f16*)(ws + OFF_H1);
  f16* uog   = (f16*)(ws + OFF_UOG);
  f16* uou   = (f16*)(ws + OFF_UOU);
  f16* utid  = (f16*)(ws + OFF_UTID);
  f16* uod   = (f16*)(ws + OFF_UOD);
  f16* h2g   = (f16*)(ws + OFF_H2G);
  f16* h2u   = (f16*)(ws + OFF_H2U);
  f16* inter = (f16*)(ws + OFF_INTER);
  f16* d1    = (f16*)(ws + OFF_D1);
  f16* d2    = (f16*)(ws + OFF_D2);
  float* downo = (float*)(ws + OFF_DOWNO);

  hipMemsetAsync(cnt, 0, NEXP*sizeof(int), stream);

  // routing chain (lpart overlays H1, dead before stage1)
  k_router4  <<<dim3(16,4,4),      256, 0, stream>>>(x, wr, lpart);
  k_topk     <<<TNUM,              256, 0, stream>>>(lpart, sel, wt, cnt);
  k_meta     <<<1,                 256, 0, stream>>>(cnt, estart, ecur, tg, hdr);
  k_scatter  <<<12,                256, 0, stream>>>(sel, ecur, row_t, pos);

  // conversions (f16, power-of-2 scales; cores transposed)
  k_cvt_all  <<<5888,              256, 0, stream>>>(x, Uog, Uou, Uod, xh, uog, uou, uod);
  k_cvt_t3   <<<dim3(4,64,24),     256, 0, stream>>>(Uig, Uiu, Uid, utig, utiu, utid);
  k_cvt_core <<<dim3(4,4,768),     256, 0, stream>>>(cg, cu, cd, cgt, cut, cdt);

  k_mm_stage1<<<dim3(16,32),       256, 0, stream>>>(xh, utig, utiu, H1);
  k_core2    <<<dim3(NEXP,2),      256, 0, stream>>>(cgt, cut, H1, estart, cnt, row_t, h2g, h2u);
  k_mm_gateup<<<dim3(MAXTILES,11), 128, 0, stream>>>(h2g, h2u, uog, uou, tg, inter);
  k_mm_down_in<<<dim3(MAXTILES,2), 256, 0, stream>>>(inter, utid, tg, d1);
  k_core_down<<<NEXP,              256, 0, stream>>>(cdt, d1, estart, cnt, d2);
  k_mm_down_out<<<dim3(MAXTILES,16),128,0, stream>>>(d2, uod, tg, downo);
  k_combine  <<<1024,              256, 0, stream>>>(downo, pos, wt, out);
}